// Round 1
// baseline (398.786 us; speedup 1.0000x reference)
//
#include <hip/hip_runtime.h>
#include <hip/hip_bf16.h>

typedef __attribute__((ext_vector_type(4))) float f32x4;
typedef __attribute__((ext_vector_type(8))) short s16x8;

typedef const __attribute__((address_space(1))) void* gptr_t;
typedef __attribute__((address_space(3))) void* lptr_t;

__device__ __forceinline__ short f2b(float f){ __hip_bfloat16 h=__float2bfloat16(f); return *(short*)&h; }
__device__ __forceinline__ float b2f(short s){ __hip_bfloat16 h; *(short*)&h = s; return __bfloat162float(h); }

__device__ __forceinline__ void gl_lds16(const void* g, void* l){
  __builtin_amdgcn_global_load_lds((gptr_t)g, (lptr_t)l, 16, 0, 0);
}

// ---------------- small prep kernels ----------------

__global__ __launch_bounds__(256) void cvt_x(const float* __restrict__ X, short* __restrict__ Xb){
  int i = blockIdx.x*256 + threadIdx.x;           // 8 elems per thread, 98304 threads
  const float4* p = (const float4*)(X + (size_t)i*8);
  float4 a = p[0], b = p[1];
  s16x8 o;
  o[0]=f2b(a.x); o[1]=f2b(a.y); o[2]=f2b(a.z); o[3]=f2b(a.w);
  o[4]=f2b(b.x); o[5]=f2b(b.y); o[6]=f2b(b.z); o[7]=f2b(b.w);
  *(s16x8*)(Xb + (size_t)i*8) = o;
}

// W fp32 [768][768] (in-dim l major) -> WT bf16 [768][768] with WT[n][l]=W[l][n]
__global__ __launch_bounds__(256) void cvt_wt(const float* __restrict__ W, short* __restrict__ WT){
  __shared__ short tile[64][72];
  int bl = blockIdx.x % 12, bn = blockIdx.x / 12;
  int l0 = bl*64, n0 = bn*64;
  int t = threadIdx.x;
  #pragma unroll
  for (int p=0;p<4;p++){
    int lr = p*16 + (t>>4);
    int nc = (t&15)*4;
    float4 v = *(const float4*)(W + (size_t)(l0+lr)*768 + n0 + nc);
    tile[lr][nc+0]=f2b(v.x); tile[lr][nc+1]=f2b(v.y); tile[lr][nc+2]=f2b(v.z); tile[lr][nc+3]=f2b(v.w);
  }
  __syncthreads();
  #pragma unroll
  for (int p=0;p<2;p++){
    int nr = p*32 + (t>>3);
    int lc = (t&7)*8;
    s16x8 o;
    #pragma unroll
    for(int u=0;u<8;u++) o[u] = tile[lc+u][nr];
    *(s16x8*)(WT + (size_t)(n0+nr)*768 + l0 + lc) = o;
  }
}

__global__ void bmask_k(const float* __restrict__ am, float* __restrict__ bmf){
  int i = blockIdx.x*256+threadIdx.x;
  if (i<1024) bmf[i] = (am[i] >= 0.0f) ? 1.0f : 0.0f;
}

// v bf16 [1024][768] -> vT bf16 [12][64][1024]
__global__ __launch_bounds__(256) void vtrans(const short* __restrict__ vs, short* __restrict__ vT){
  __shared__ short tile[64][72];
  int h = blockIdx.y; int i0 = blockIdx.x*64;
  int t = threadIdx.x;
  #pragma unroll
  for(int p=0;p<2;p++){
    int ir = p*32 + (t>>3); int c8=(t&7)*8;
    *(s16x8*)&tile[ir][c8] = *(const s16x8*)(vs + (size_t)(i0+ir)*768 + h*64 + c8);
  }
  __syncthreads();
  #pragma unroll
  for(int p=0;p<2;p++){
    int dr = p*32 + (t>>3); int i8=(t&7)*8;
    s16x8 o;
    #pragma unroll
    for(int u=0;u<8;u++) o[u]=tile[i8+u][dr];
    *(s16x8*)(vT + ((size_t)h*64 + dr)*1024 + i0 + i8) = o;
  }
}

// ---------------- QKV projection GEMM (bf16 MFMA, gemm_bt) ----------------
// M=1024,N=768,K=768. blockIdx.y selects q/k/v.
__global__ __launch_bounds__(256) void qkv_gemm(const short* __restrict__ Xb, const short* __restrict__ WT,
      const float* __restrict__ bq, const float* __restrict__ bk, const float* __restrict__ bv,
      short* __restrict__ qs, short* __restrict__ ks, short* __restrict__ vs){
  __shared__ short lA[128*32], lB[128*32];
  int mat = blockIdx.y;
  const short* B = WT + (size_t)mat*768*768;
  const float* bias = mat==0?bq:(mat==1?bk:bv);
  short* outp = mat==0?qs:(mat==1?ks:vs);
  float scale = mat==0 ? 0.125f : 1.0f;
  int tm = (blockIdx.x / 6)*128, tn = (blockIdx.x % 6)*128;
  int t=threadIdx.x, wave=t>>6, lane=t&63;
  int srow=t>>2, scol=(t&3)*8;
  int wm=(wave>>1)*64, wn=(wave&1)*64;
  f32x4 acc[4][4]={};
  for (int k0=0;k0<768;k0+=32){
    #pragma unroll
    for(int r=0;r<2;++r){
      gl_lds16(Xb + (size_t)(tm+srow+r*64)*768 + k0 + scol, lA + r*2048 + wave*512);
      gl_lds16(B  + (size_t)(tn+srow+r*64)*768 + k0 + scol, lB + r*2048 + wave*512);
    }
    __syncthreads();
    int krow=(lane>>4)*8, rl=lane&15;
    s16x8 af[4], bfr[4];
    #pragma unroll
    for(int m=0;m<4;m++) af[m] = *(s16x8*)&lA[(wm+m*16+rl)*32 + krow];
    #pragma unroll
    for(int n=0;n<4;n++) bfr[n] = *(s16x8*)&lB[(wn+n*16+rl)*32 + krow];
    #pragma unroll
    for(int m=0;m<4;m++)
      #pragma unroll
      for(int n=0;n<4;n++)
        acc[m][n]=__builtin_amdgcn_mfma_f32_16x16x32_bf16(af[m],bfr[n],acc[m][n],0,0,0);
    __syncthreads();
  }
  int r0 = tm + wm + (lane>>4)*4, c0 = tn + wn + (lane&15);
  #pragma unroll
  for(int m=0;m<4;m++)
    #pragma unroll
    for(int n=0;n<4;n++){
      int col = c0 + n*16; float bb = bias[col];
      #pragma unroll
      for(int r=0;r<4;r++){
        int row = r0 + m*16 + r;
        outp[(size_t)row*768 + col] = f2b((acc[m][n][r] + bb)*scale);
      }
    }
}

// ---------------- W_G = exp(K Q^T) masked, + row sums ----------------
__global__ __launch_bounds__(256) void wg_gemm(const short* __restrict__ kb, const short* __restrict__ qb,
      const int* __restrict__ g, const float* __restrict__ bmf,
      short* __restrict__ WG, float* __restrict__ od){
  __shared__ short lK[128*64], lQ[128*64];
  int h=blockIdx.y;
  int tm=(blockIdx.x>>3)*128, tn=(blockIdx.x&7)*128;
  int t=threadIdx.x, wave=t>>6, lane=t&63;
  int srow=t>>3, scol=(t&7)*8;
  int wm=(wave>>1)*64, wn=(wave&1)*64;
  #pragma unroll
  for(int r=0;r<4;++r){
    gl_lds16(kb + (size_t)(tm+srow+r*32)*768 + h*64 + scol, lK + r*2048 + wave*512);
    gl_lds16(qb + (size_t)(tn+srow+r*32)*768 + h*64 + scol, lQ + r*2048 + wave*512);
  }
  __syncthreads();
  int rl=lane&15;
  f32x4 acc[4][4]={};
  #pragma unroll
  for(int ks=0;ks<2;ks++){
    int krow=ks*32+(lane>>4)*8;
    s16x8 af[4], bfr[4];
    #pragma unroll
    for(int m=0;m<4;m++) af[m]=*(s16x8*)&lK[(wm+m*16+rl)*64+krow];
    #pragma unroll
    for(int n=0;n<4;n++) bfr[n]=*(s16x8*)&lQ[(wn+n*16+rl)*64+krow];
    #pragma unroll
    for(int m=0;m<4;m++)
      #pragma unroll
      for(int n=0;n<4;n++)
        acc[m][n]=__builtin_amdgcn_mfma_f32_16x16x32_bf16(af[m],bfr[n],acc[m][n],0,0,0);
  }
  size_t hm=(size_t)h<<20;
  int r0=tm+wm+(lane>>4)*4, c0=tn+wn+rl;
  #pragma unroll
  for(int m=0;m<4;m++){
    float rs[4]={0.f,0.f,0.f,0.f};
    #pragma unroll
    for(int n=0;n<4;n++){
      int col=c0+n*16;
      float mc = bmf[col];
      #pragma unroll
      for(int r=0;r<4;r++){
        int row=r0+m*16+r;
        float e = expf(acc[m][n][r]);
        float w = (g[(size_t)row*1024+col]>0 && bmf[row]>0.f && mc>0.f) ? e : 0.f;
        WG[hm+(size_t)row*1024+col]=f2b(w);
        rs[r]+=w;
      }
    }
    #pragma unroll
    for(int r=0;r<4;r++){
      float s=rs[r];
      #pragma unroll
      for(int off=1;off<16;off<<=1) s+=__shfl_xor(s,off);
      if(rl==0) atomicAdd(&od[(h<<10)+r0+m*16+r], s);
    }
  }
}

__global__ void rhos_k(const float* __restrict__ od, float* __restrict__ rhos){
  __shared__ float red[256];
  int h = blockIdx.x, t = threadIdx.x;
  float m = -1e30f;
  for (int i=t;i<1024;i+=256) m = fmaxf(m, od[(h<<10)+i]);
  red[t]=m; __syncthreads();
  for(int s=128;s>0;s>>=1){ if(t<s) red[t]=fmaxf(red[t],red[t+s]); __syncthreads(); }
  if(t==0) rhos[h]=red[0];
}

// Amat = (W_G + diag(rho - od)) / rho   (row-stochastic, bf16)
__global__ __launch_bounds__(256) void amat_k(const short* __restrict__ WG, const float* __restrict__ od,
      const float* __restrict__ rhos, short* __restrict__ Am){
  int idx = blockIdx.x*256 + threadIdx.x;   // 12*1024*128
  int j8 = (idx & 127)*8;
  int i  = (idx >> 7) & 1023;
  int h  = idx >> 17;
  float inv = 1.0f / fmaxf(rhos[h], 1e-30f);
  size_t base = ((size_t)h<<20) + (size_t)i*1024 + j8;
  s16x8 w = *(const s16x8*)(WG + base);
  s16x8 o;
  #pragma unroll
  for(int u=0;u<8;u++) o[u]=f2b(b2f(w[u])*inv);
  if ((unsigned)(i - j8) < 8u){
    int u=i-j8;
    o[u]=f2b(b2f(w[u])*inv + (rhos[h]-od[(h<<10)+i])*inv);
  }
  *(s16x8*)(Am + base) = o;
}

__global__ void diag_k(short* __restrict__ P, float val){
  int idx = blockIdx.x*256+threadIdx.x;
  if (idx < 12288){ int h=idx>>10, i=idx&1023; P[((size_t)h<<20) + (size_t)i*1024 + i] = f2b(val); }
}

// ---------------- big power-series GEMM: D = gemm_bt(A,B) + diag*I, per head ----------------
__global__ __launch_bounds__(256) void gemm_pow(const short* __restrict__ A, const short* __restrict__ B,
      short* __restrict__ D, float diag){
  __shared__ short lA[128*32], lB[128*32];
  int h=blockIdx.y;
  int tm=(blockIdx.x>>3)*128, tn=(blockIdx.x&7)*128;
  size_t hm=(size_t)h<<20;
  int t=threadIdx.x, wave=t>>6, lane=t&63;
  int srow=t>>2, scol=(t&3)*8;
  int wm=(wave>>1)*64, wn=(wave&1)*64;
  f32x4 acc[4][4]={};
  for(int k0=0;k0<1024;k0+=32){
    #pragma unroll
    for(int r=0;r<2;++r){
      gl_lds16(A + hm + (size_t)(tm+srow+r*64)*1024 + k0 + scol, lA + r*2048 + wave*512);
      gl_lds16(B + hm + (size_t)(tn+srow+r*64)*1024 + k0 + scol, lB + r*2048 + wave*512);
    }
    __syncthreads();
    int krow=(lane>>4)*8, rl=lane&15;
    s16x8 af[4], bfr[4];
    #pragma unroll
    for(int m=0;m<4;m++) af[m]=*(s16x8*)&lA[(wm+m*16+rl)*32+krow];
    #pragma unroll
    for(int n=0;n<4;n++) bfr[n]=*(s16x8*)&lB[(wn+n*16+rl)*32+krow];
    #pragma unroll
    for(int m=0;m<4;m++)
      #pragma unroll
      for(int n=0;n<4;n++)
        acc[m][n]=__builtin_amdgcn_mfma_f32_16x16x32_bf16(af[m],bfr[n],acc[m][n],0,0,0);
    __syncthreads();
  }
  int r0=tm+wm+(lane>>4)*4, c0=tn+wn+(lane&15);
  #pragma unroll
  for(int m=0;m<4;m++)
    #pragma unroll
    for(int n=0;n<4;n++){
      int col=c0+n*16;
      #pragma unroll
      for(int r=0;r<4;r++){
        int row=r0+m*16+r;
        float v=acc[m][n][r];
        if(row==col) v+=diag;
        D[hm + (size_t)row*1024 + col]=f2b(v);
      }
    }
}

// per-row stats of L: dv = L[i,i], invr = 1/max(sum_{j!=i}|L[i,j]|, 1e-12)
__global__ __launch_bounds__(256) void rowstat_k(const short* __restrict__ L, float* __restrict__ dv,
      float* __restrict__ invr){
  int t=threadIdx.x, wave=t>>6, lane=t&63;
  int rowg = blockIdx.x*4 + wave;
  int h = rowg>>10, i = rowg&1023;
  const short* Lr = L + ((size_t)h<<20) + (size_t)i*1024;
  float s=0.f;
  #pragma unroll
  for(int c=0;c<2;c++){
    s16x8 v = *(const s16x8*)(Lr + lane*16 + c*8);
    #pragma unroll
    for(int u=0;u<8;u++) s += fabsf(b2f(v[u]));
  }
  #pragma unroll
  for(int off=1;off<64;off<<=1) s += __shfl_xor(s, off);
  if(lane==0){
    float d = b2f(Lr[i]);
    dv[rowg]=d;
    invr[rowg]=1.0f/fmaxf(s - fabsf(d), 1e-12f);
  }
}

// ---------------- final: attn = .8*(WG/od)@v + .2*(d_i v_i - L@v)/r_i ----------------
__global__ __launch_bounds__(256) void attn_k(const short* __restrict__ WG, const short* __restrict__ L,
    const short* __restrict__ vT, const short* __restrict__ vs,
    const float* __restrict__ od, const float* __restrict__ dv, const float* __restrict__ invr,
    float* __restrict__ out){
  __shared__ short lW[128*32], lL[128*32], lV[64*32];
  int h=blockIdx.y, tm=blockIdx.x*128;
  size_t hm=(size_t)h<<20;
  int t=threadIdx.x, wave=t>>6, lane=t&63;
  int srow=t>>2, scol=(t&3)*8;
  f32x4 a1[2][4]={}, a2[2][4]={};
  for(int j0=0;j0<1024;j0+=32){
    #pragma unroll
    for(int r=0;r<2;++r){
      gl_lds16(WG + hm + (size_t)(tm+srow+r*64)*1024 + j0 + scol, lW + r*2048 + wave*512);
      gl_lds16(L  + hm + (size_t)(tm+srow+r*64)*1024 + j0 + scol, lL + r*2048 + wave*512);
    }
    gl_lds16(vT + ((size_t)h*64 + srow)*1024 + j0 + scol, lV + wave*512);
    __syncthreads();
    int krow=(lane>>4)*8, rl=lane&15;
    s16x8 fw[2], fl[2], fv[4];
    #pragma unroll
    for(int m=0;m<2;m++){
      fw[m]=*(s16x8*)&lW[(wave*32+m*16+rl)*32+krow];
      fl[m]=*(s16x8*)&lL[(wave*32+m*16+rl)*32+krow];
    }
    #pragma unroll
    for(int n=0;n<4;n++) fv[n]=*(s16x8*)&lV[(n*16+rl)*32+krow];
    #pragma unroll
    for(int m=0;m<2;m++)
      #pragma unroll
      for(int n=0;n<4;n++){
        a1[m][n]=__builtin_amdgcn_mfma_f32_16x16x32_bf16(fw[m],fv[n],a1[m][n],0,0,0);
        a2[m][n]=__builtin_amdgcn_mfma_f32_16x16x32_bf16(fl[m],fv[n],a2[m][n],0,0,0);
      }
    __syncthreads();
  }
  #pragma unroll
  for(int m=0;m<2;m++)
    #pragma unroll
    for(int r=0;r<4;r++){
      int row = tm + wave*32 + m*16 + (lane>>4)*4 + r;
      float invod = 1.0f/fmaxf(od[(h<<10)+row], 1e-12f);
      float dvi = dv[(h<<10)+row], ivr = invr[(h<<10)+row];
      #pragma unroll
      for(int n=0;n<4;n++){
        int d = n*16 + (lane&15);
        float vv = b2f(vs[(size_t)row*768 + h*64 + d]);
        out[(((size_t)h<<10)+row)*64 + d] = 0.8f*a1[m][n][r]*invod + 0.2f*(dvi*vv - a2[m][n][r])*ivr;
      }
    }
}

// ---------------- launch ----------------
extern "C" void kernel_launch(void* const* d_in, const int* in_sizes, int n_in,
                              void* d_out, int out_size, void* d_ws, size_t ws_size,
                              hipStream_t stream){
  const float* hs = (const float*)d_in[0];
  const float* Wq = (const float*)d_in[1];
  const float* bq = (const float*)d_in[2];
  const float* Wk = (const float*)d_in[3];
  const float* bk = (const float*)d_in[4];
  const float* Wv = (const float*)d_in[5];
  const float* bv = (const float*)d_in[6];
  const int*   g  = (const int*)d_in[7];
  const float* am = (const float*)d_in[8];
  float* out = (float*)d_out;

  char* w = (char*)d_ws;
  auto alloc=[&](size_t bytes)->char*{ char* p=w; w += (bytes+255)&~(size_t)255; return p; };
  short* Xb  = (short*)alloc((size_t)1024*768*2);
  short* WT  = (short*)alloc((size_t)3*768*768*2);
  short* qs  = (short*)alloc((size_t)1024*768*2);
  short* ks  = (short*)alloc((size_t)1024*768*2);
  short* vs  = (short*)alloc((size_t)1024*768*2);
  short* vT  = (short*)alloc((size_t)12*64*1024*2);
  short* WG  = (short*)alloc((size_t)12*1024*1024*2);
  short* Am  = (short*)alloc((size_t)12*1024*1024*2);
  short* P0  = (short*)alloc((size_t)12*1024*1024*2);
  short* P1  = (short*)alloc((size_t)12*1024*1024*2);
  float* od  = (float*)alloc((size_t)12*1024*4);
  float* rh  = (float*)alloc((size_t)64*4);
  float* bmf = (float*)alloc((size_t)1024*4);
  float* dv  = (float*)alloc((size_t)12*1024*4);
  float* ivr = (float*)alloc((size_t)12*1024*4);

  hipMemsetAsync(od, 0, (size_t)12*1024*4, stream);
  hipMemsetAsync(P0, 0, (size_t)12*1024*1024*2, stream);

  cvt_x<<<384,256,0,stream>>>(hs, Xb);
  cvt_wt<<<144,256,0,stream>>>(Wq, WT);
  cvt_wt<<<144,256,0,stream>>>(Wk, WT + (size_t)768*768);
  cvt_wt<<<144,256,0,stream>>>(Wv, WT + (size_t)2*768*768);
  bmask_k<<<4,256,0,stream>>>(am, bmf);
  qkv_gemm<<<dim3(48,3),256,0,stream>>>(Xb, WT, bq,bk,bv, qs,ks,vs);
  vtrans<<<dim3(16,12),256,0,stream>>>(vs, vT);
  wg_gemm<<<dim3(64,12),256,0,stream>>>(ks, qs, g, bmf, WG, od);
  rhos_k<<<12,256,0,stream>>>(od, rh);
  amat_k<<<6144,256,0,stream>>>(WG, od, rh, Am);
  diag_k<<<48,256,0,stream>>>(P0, -33.0f/2048.0f);   // St7 = b7*I

  const float bcoef[6] = {-21.f/1024.f, -7.f/256.f, -5.f/128.f, -1.f/16.f, -1.f/8.f, -0.5f};
  short* pin=P0; short* pout=P1;
  for(int s=0;s<6;s++){
    gemm_pow<<<dim3(64,12),256,0,stream>>>(pin, Am, pout, bcoef[s]);  // St_k = b_k I + (A S)^T
    short* tmp=pin; pin=pout; pout=tmp;
  }
  gemm_pow<<<dim3(64,12),256,0,stream>>>(Am, pin, pout, 1.0f);        // L = I + A*S1 (row-major)
  short* L = pout;

  rowstat_k<<<3072,256,0,stream>>>(L, dv, ivr);
  attn_k<<<dim3(8,12),256,0,stream>>>(WG, L, vT, vs, od, dv, ivr, out);
}

// Round 2
// 318.826 us; speedup vs baseline: 1.2508x; 1.2508x over previous
//
#include <hip/hip_runtime.h>
#include <hip/hip_bf16.h>

typedef __attribute__((ext_vector_type(4))) float f32x4;
typedef __attribute__((ext_vector_type(8))) short s16x8;

typedef const __attribute__((address_space(1))) void* gptr_t;
typedef __attribute__((address_space(3))) void* lptr_t;

__device__ __forceinline__ short f2b(float f){ __hip_bfloat16 h=__float2bfloat16(f); return *(short*)&h; }
__device__ __forceinline__ float b2f(short s){ __hip_bfloat16 h; *(short*)&h = s; return __bfloat162float(h); }

__device__ __forceinline__ void gl_lds16(const void* g, void* l){
  __builtin_amdgcn_global_load_lds((gptr_t)g, (lptr_t)l, 16, 0, 0);
}

// ---------------- small prep kernels ----------------

__global__ __launch_bounds__(256) void cvt_x(const float* __restrict__ X, short* __restrict__ Xb){
  int i = blockIdx.x*256 + threadIdx.x;
  const float4* p = (const float4*)(X + (size_t)i*8);
  float4 a = p[0], b = p[1];
  s16x8 o;
  o[0]=f2b(a.x); o[1]=f2b(a.y); o[2]=f2b(a.z); o[3]=f2b(a.w);
  o[4]=f2b(b.x); o[5]=f2b(b.y); o[6]=f2b(b.z); o[7]=f2b(b.w);
  *(s16x8*)(Xb + (size_t)i*8) = o;
}

// W fp32 [768][768] -> WT bf16 [768][768] with WT[n][l]=W[l][n]
__global__ __launch_bounds__(256) void cvt_wt(const float* __restrict__ W, short* __restrict__ WT){
  __shared__ short tile[64][72];
  int bl = blockIdx.x % 12, bn = blockIdx.x / 12;
  int l0 = bl*64, n0 = bn*64;
  int t = threadIdx.x;
  #pragma unroll
  for (int p=0;p<4;p++){
    int lr = p*16 + (t>>4);
    int nc = (t&15)*4;
    float4 v = *(const float4*)(W + (size_t)(l0+lr)*768 + n0 + nc);
    tile[lr][nc+0]=f2b(v.x); tile[lr][nc+1]=f2b(v.y); tile[lr][nc+2]=f2b(v.z); tile[lr][nc+3]=f2b(v.w);
  }
  __syncthreads();
  #pragma unroll
  for (int p=0;p<2;p++){
    int nr = p*32 + (t>>3);
    int lc = (t&7)*8;
    s16x8 o;
    #pragma unroll
    for(int u=0;u<8;u++) o[u] = tile[lc+u][nr];
    *(s16x8*)(WT + (size_t)(n0+nr)*768 + l0 + lc) = o;
  }
}

__global__ void bmask_k(const float* __restrict__ am, float* __restrict__ bmf){
  int i = blockIdx.x*256+threadIdx.x;
  if (i<1024) bmf[i] = (am[i] >= 0.0f) ? 1.0f : 0.0f;
}

// v bf16 [1024][768] -> vT bf16 [12][64][1024]
__global__ __launch_bounds__(256) void vtrans(const short* __restrict__ vs, short* __restrict__ vT){
  __shared__ short tile[64][72];
  int h = blockIdx.y; int i0 = blockIdx.x*64;
  int t = threadIdx.x;
  #pragma unroll
  for(int p=0;p<2;p++){
    int ir = p*32 + (t>>3); int c8=(t&7)*8;
    *(s16x8*)&tile[ir][c8] = *(const s16x8*)(vs + (size_t)(i0+ir)*768 + h*64 + c8);
  }
  __syncthreads();
  #pragma unroll
  for(int p=0;p<2;p++){
    int dr = p*32 + (t>>3); int i8=(t&7)*8;
    s16x8 o;
    #pragma unroll
    for(int u=0;u<8;u++) o[u]=tile[i8+u][dr];
    *(s16x8*)(vT + ((size_t)h*64 + dr)*1024 + i0 + i8) = o;
  }
}

// ---------------- QKV projection GEMM ----------------
__global__ __launch_bounds__(256) void qkv_gemm(const short* __restrict__ Xb, const short* __restrict__ WT,
      const float* __restrict__ bq, const float* __restrict__ bk, const float* __restrict__ bv,
      short* __restrict__ qs, short* __restrict__ ks, short* __restrict__ vs){
  __shared__ short lA[128*32], lB[128*32];
  int mat = blockIdx.y;
  const short* B = WT + (size_t)mat*768*768;
  const float* bias = mat==0?bq:(mat==1?bk:bv);
  short* outp = mat==0?qs:(mat==1?ks:vs);
  float scale = mat==0 ? 0.125f : 1.0f;
  int tm = (blockIdx.x / 6)*128, tn = (blockIdx.x % 6)*128;
  int t=threadIdx.x, wave=t>>6, lane=t&63;
  int srow=t>>2, scol=(t&3)*8;
  int wm=(wave>>1)*64, wn=(wave&1)*64;
  f32x4 acc[4][4]={};
  for (int k0=0;k0<768;k0+=32){
    #pragma unroll
    for(int r=0;r<2;++r){
      gl_lds16(Xb + (size_t)(tm+srow+r*64)*768 + k0 + scol, lA + r*2048 + wave*512);
      gl_lds16(B  + (size_t)(tn+srow+r*64)*768 + k0 + scol, lB + r*2048 + wave*512);
    }
    __syncthreads();
    int krow=(lane>>4)*8, rl=lane&15;
    s16x8 af[4], bfr[4];
    #pragma unroll
    for(int m=0;m<4;m++) af[m] = *(s16x8*)&lA[(wm+m*16+rl)*32 + krow];
    #pragma unroll
    for(int n=0;n<4;n++) bfr[n] = *(s16x8*)&lB[(wn+n*16+rl)*32 + krow];
    #pragma unroll
    for(int m=0;m<4;m++)
      #pragma unroll
      for(int n=0;n<4;n++)
        acc[m][n]=__builtin_amdgcn_mfma_f32_16x16x32_bf16(af[m],bfr[n],acc[m][n],0,0,0);
    __syncthreads();
  }
  int r0 = tm + wm + (lane>>4)*4, c0 = tn + wn + (lane&15);
  #pragma unroll
  for(int m=0;m<4;m++)
    #pragma unroll
    for(int n=0;n<4;n++){
      int col = c0 + n*16; float bb = bias[col];
      #pragma unroll
      for(int r=0;r<4;r++){
        int row = r0 + m*16 + r;
        outp[(size_t)row*768 + col] = f2b((acc[m][n][r] + bb)*scale);
      }
    }
}

// ---------------- W_G = exp(K Q^T) masked, + row sums ----------------
__global__ __launch_bounds__(256) void wg_gemm(const short* __restrict__ kb, const short* __restrict__ qb,
      const int* __restrict__ g, const float* __restrict__ bmf,
      short* __restrict__ WG, float* __restrict__ od){
  __shared__ short lK[128*64], lQ[128*64];
  int h=blockIdx.y;
  int tm=(blockIdx.x>>3)*128, tn=(blockIdx.x&7)*128;
  int t=threadIdx.x, wave=t>>6, lane=t&63;
  int srow=t>>3, scol=(t&7)*8;
  int wm=(wave>>1)*64, wn=(wave&1)*64;
  #pragma unroll
  for(int r=0;r<4;++r){
    gl_lds16(kb + (size_t)(tm+srow+r*32)*768 + h*64 + scol, lK + r*2048 + wave*512);
    gl_lds16(qb + (size_t)(tn+srow+r*32)*768 + h*64 + scol, lQ + r*2048 + wave*512);
  }
  __syncthreads();
  int rl=lane&15;
  f32x4 acc[4][4]={};
  #pragma unroll
  for(int ks=0;ks<2;ks++){
    int krow=ks*32+(lane>>4)*8;
    s16x8 af[4], bfr[4];
    #pragma unroll
    for(int m=0;m<4;m++) af[m]=*(s16x8*)&lK[(wm+m*16+rl)*64+krow];
    #pragma unroll
    for(int n=0;n<4;n++) bfr[n]=*(s16x8*)&lQ[(wn+n*16+rl)*64+krow];
    #pragma unroll
    for(int m=0;m<4;m++)
      #pragma unroll
      for(int n=0;n<4;n++)
        acc[m][n]=__builtin_amdgcn_mfma_f32_16x16x32_bf16(af[m],bfr[n],acc[m][n],0,0,0);
  }
  size_t hm=(size_t)h<<20;
  int r0=tm+wm+(lane>>4)*4, c0=tn+wn+rl;
  #pragma unroll
  for(int m=0;m<4;m++){
    float rs[4]={0.f,0.f,0.f,0.f};
    #pragma unroll
    for(int n=0;n<4;n++){
      int col=c0+n*16;
      float mc = bmf[col];
      #pragma unroll
      for(int r=0;r<4;r++){
        int row=r0+m*16+r;
        float e = expf(acc[m][n][r]);
        float w = (g[(size_t)row*1024+col]>0 && bmf[row]>0.f && mc>0.f) ? e : 0.f;
        WG[hm+(size_t)row*1024+col]=f2b(w);
        rs[r]+=w;
      }
    }
    #pragma unroll
    for(int r=0;r<4;r++){
      float s=rs[r];
      #pragma unroll
      for(int off=1;off<16;off<<=1) s+=__shfl_xor(s,off);
      if(rl==0) atomicAdd(&od[(h<<10)+r0+m*16+r], s);
    }
  }
}

__global__ void rhos_k(const float* __restrict__ od, float* __restrict__ rhos){
  __shared__ float red[256];
  int h = blockIdx.x, t = threadIdx.x;
  float m = -1e30f;
  for (int i=t;i<1024;i+=256) m = fmaxf(m, od[(h<<10)+i]);
  red[t]=m; __syncthreads();
  for(int s=128;s>0;s>>=1){ if(t<s) red[t]=fmaxf(red[t],red[t+s]); __syncthreads(); }
  if(t==0) rhos[h]=red[0];
}

// Am = (WG + diag(rho-od))/rho ; AmT = Am^T ; T = b7*Am + b6*I  (one tiled pass)
__global__ __launch_bounds__(256) void amat_t(const short* __restrict__ WG, const float* __restrict__ od,
      const float* __restrict__ rhos, short* __restrict__ Am, short* __restrict__ AmT,
      short* __restrict__ T){
  __shared__ short tile[64][72];
  const float b7 = -33.f/2048.f, b6 = -21.f/1024.f;
  int h = blockIdx.y; int bx = blockIdx.x;
  int rb = bx >> 4, cb = bx & 15;
  int r0 = rb*64, c0 = cb*64;
  float rho = rhos[h]; float inv = 1.0f/fmaxf(rho,1e-30f);
  size_t hm = (size_t)h<<20;
  int t = threadIdx.x;
  #pragma unroll
  for(int p=0;p<2;p++){
    int r = p*32 + (t>>3); int c8 = (t&7)*8;
    size_t base = hm + (size_t)(r0+r)*1024 + c0 + c8;
    s16x8 w = *(const s16x8*)(WG + base);
    s16x8 oa, ot;
    float dadd = (rho - od[(h<<10)+r0+r])*inv;
    #pragma unroll
    for(int u=0;u<8;u++){
      bool dg = (rb==cb) && ((c8+u)==r);
      float a = b2f(w[u])*inv + (dg ? dadd : 0.f);
      oa[u]=f2b(a);
      ot[u]=f2b(b7*a + (dg ? b6 : 0.f));
      tile[r][c8+u]=oa[u];
    }
    *(s16x8*)(Am+base)=oa; *(s16x8*)(T+base)=ot;
  }
  __syncthreads();
  #pragma unroll
  for(int p=0;p<2;p++){
    int c = p*32 + (t>>3); int r8 = (t&7)*8;
    s16x8 o;
    #pragma unroll
    for(int u=0;u<8;u++) o[u]=tile[r8+u][c];
    *(s16x8*)(AmT + hm + (size_t)(c0+c)*1024 + r0 + r8) = o;
  }
}

// ---------------- Paterson-Stockmeyer GEMM: D = X*Y^T [+ c0*I + cA*E1 + cB*E2] ----------------
// EPI=0: plain store. EPI=1: epilogue linear combo; STAT: fused row |L| sums + diagonal.
template<int EPI, bool STAT>
__global__ __launch_bounds__(256) void gemm_ps(const short* __restrict__ A, const short* __restrict__ B,
      short* __restrict__ D, const short* __restrict__ E1, const short* __restrict__ E2,
      float c0c, float cA, float cB, float* __restrict__ rowabs, float* __restrict__ dvp){
  __shared__ short lA[128*32], lB[128*32];
  int h=blockIdx.y;
  int tm=(blockIdx.x>>3)*128, tn=(blockIdx.x&7)*128;
  size_t hm=(size_t)h<<20;
  int t=threadIdx.x, wave=t>>6, lane=t&63;
  int srow=t>>2, scol=(t&3)*8;
  int wm=(wave>>1)*64, wn=(wave&1)*64;
  f32x4 acc[4][4]={};
  for(int k0=0;k0<1024;k0+=32){
    #pragma unroll
    for(int r=0;r<2;++r){
      gl_lds16(A + hm + (size_t)(tm+srow+r*64)*1024 + k0 + scol, lA + r*2048 + wave*512);
      gl_lds16(B + hm + (size_t)(tn+srow+r*64)*1024 + k0 + scol, lB + r*2048 + wave*512);
    }
    __syncthreads();
    int krow=(lane>>4)*8, rl=lane&15;
    s16x8 af[4], bfr[4];
    #pragma unroll
    for(int m=0;m<4;m++) af[m]=*(s16x8*)&lA[(wm+m*16+rl)*32+krow];
    #pragma unroll
    for(int n=0;n<4;n++) bfr[n]=*(s16x8*)&lB[(wn+n*16+rl)*32+krow];
    #pragma unroll
    for(int m=0;m<4;m++)
      #pragma unroll
      for(int n=0;n<4;n++)
        acc[m][n]=__builtin_amdgcn_mfma_f32_16x16x32_bf16(af[m],bfr[n],acc[m][n],0,0,0);
    __syncthreads();
  }
  int r0=tm+wm+(lane>>4)*4, c0=tn+wn+(lane&15);
  int rl=lane&15;
  #pragma unroll
  for(int m=0;m<4;m++){
    float rs[4]={0.f,0.f,0.f,0.f};
    #pragma unroll
    for(int n=0;n<4;n++){
      int col=c0+n*16;
      #pragma unroll
      for(int r=0;r<4;r++){
        int row=r0+m*16+r;
        float v=acc[m][n][r];
        if (EPI==1){
          size_t e = hm + (size_t)row*1024 + col;
          v += cA*b2f(E1[e]) + cB*b2f(E2[e]);
          if(row==col) v += c0c;
        }
        if (STAT){
          rs[r] += fabsf(v);
          if(row==col) dvp[(h<<10)+row] = v;
        }
        D[hm + (size_t)row*1024 + col]=f2b(v);
      }
    }
    if (STAT){
      #pragma unroll
      for(int r=0;r<4;r++){
        float s=rs[r];
        #pragma unroll
        for(int off=1;off<16;off<<=1) s+=__shfl_xor(s,off);
        if(rl==0) atomicAdd(&rowabs[(h<<10)+r0+m*16+r], s);
      }
    }
  }
}

// ---------------- final: attn = .8*(WG/od)@v + .2*(d_i v_i - L@v)/r_i ----------------
__global__ __launch_bounds__(256) void attn_k(const short* __restrict__ WG, const short* __restrict__ L,
    const short* __restrict__ vT, const short* __restrict__ vs,
    const float* __restrict__ od, const float* __restrict__ dv, const float* __restrict__ rowabs,
    float* __restrict__ out){
  __shared__ short lW[128*32], lL[128*32], lV[64*32];
  int h=blockIdx.y, tm=blockIdx.x*128;
  size_t hm=(size_t)h<<20;
  int t=threadIdx.x, wave=t>>6, lane=t&63;
  int srow=t>>2, scol=(t&3)*8;
  f32x4 a1[2][4]={}, a2[2][4]={};
  for(int j0=0;j0<1024;j0+=32){
    #pragma unroll
    for(int r=0;r<2;++r){
      gl_lds16(WG + hm + (size_t)(tm+srow+r*64)*1024 + j0 + scol, lW + r*2048 + wave*512);
      gl_lds16(L  + hm + (size_t)(tm+srow+r*64)*1024 + j0 + scol, lL + r*2048 + wave*512);
    }
    gl_lds16(vT + ((size_t)h*64 + srow)*1024 + j0 + scol, lV + wave*512);
    __syncthreads();
    int krow=(lane>>4)*8, rl=lane&15;
    s16x8 fw[2], fl[2], fv[4];
    #pragma unroll
    for(int m=0;m<2;m++){
      fw[m]=*(s16x8*)&lW[(wave*32+m*16+rl)*32+krow];
      fl[m]=*(s16x8*)&lL[(wave*32+m*16+rl)*32+krow];
    }
    #pragma unroll
    for(int n=0;n<4;n++) fv[n]=*(s16x8*)&lV[(n*16+rl)*32+krow];
    #pragma unroll
    for(int m=0;m<2;m++)
      #pragma unroll
      for(int n=0;n<4;n++){
        a1[m][n]=__builtin_amdgcn_mfma_f32_16x16x32_bf16(fw[m],fv[n],a1[m][n],0,0,0);
        a2[m][n]=__builtin_amdgcn_mfma_f32_16x16x32_bf16(fl[m],fv[n],a2[m][n],0,0,0);
      }
    __syncthreads();
  }
  #pragma unroll
  for(int m=0;m<2;m++)
    #pragma unroll
    for(int r=0;r<4;r++){
      int row = tm + wave*32 + m*16 + (lane>>4)*4 + r;
      float invod = 1.0f/fmaxf(od[(h<<10)+row], 1e-12f);
      float dvi = dv[(h<<10)+row];
      float ivr = 1.0f/fmaxf(rowabs[(h<<10)+row] - fabsf(dvi), 1e-12f);
      #pragma unroll
      for(int n=0;n<4;n++){
        int d = n*16 + (lane&15);
        float vv = b2f(vs[(size_t)row*768 + h*64 + d]);
        out[(((size_t)h<<10)+row)*64 + d] = 0.8f*a1[m][n][r]*invod + 0.2f*(dvi*vv - a2[m][n][r])*ivr;
      }
    }
}

// ---------------- launch ----------------
extern "C" void kernel_launch(void* const* d_in, const int* in_sizes, int n_in,
                              void* d_out, int out_size, void* d_ws, size_t ws_size,
                              hipStream_t stream){
  const float* hs = (const float*)d_in[0];
  const float* Wq = (const float*)d_in[1];
  const float* bq = (const float*)d_in[2];
  const float* Wk = (const float*)d_in[3];
  const float* bk = (const float*)d_in[4];
  const float* Wv = (const float*)d_in[5];
  const float* bv = (const float*)d_in[6];
  const int*   g  = (const int*)d_in[7];
  const float* am = (const float*)d_in[8];
  float* out = (float*)d_out;

  char* w = (char*)d_ws;
  auto alloc=[&](size_t bytes)->char*{ char* p=w; w += (bytes+255)&~(size_t)255; return p; };
  short* Xb  = (short*)alloc((size_t)1024*768*2);
  short* WT  = (short*)alloc((size_t)3*768*768*2);
  short* qs  = (short*)alloc((size_t)1024*768*2);
  short* ks  = (short*)alloc((size_t)1024*768*2);
  short* vs  = (short*)alloc((size_t)1024*768*2);
  short* vT  = (short*)alloc((size_t)12*64*1024*2);
  short* WG  = (short*)alloc((size_t)12*1024*1024*2);
  short* Am  = (short*)alloc((size_t)12*1024*1024*2);
  short* AmT = (short*)alloc((size_t)12*1024*1024*2);  // later reused as V
  short* Tm  = (short*)alloc((size_t)12*1024*1024*2);  // later reused as L
  short* A2  = (short*)alloc((size_t)12*1024*1024*2);
  short* A3T = (short*)alloc((size_t)12*1024*1024*2);
  float* od  = (float*)alloc((size_t)12*1024*4);
  float* rh  = (float*)alloc((size_t)64*4);
  float* bmf = (float*)alloc((size_t)1024*4);
  float* dv  = (float*)alloc((size_t)12*1024*4);
  float* rab = (float*)alloc((size_t)12*1024*4);

  hipMemsetAsync(od,  0, (size_t)12*1024*4, stream);
  hipMemsetAsync(rab, 0, (size_t)12*1024*4, stream);

  cvt_x<<<384,256,0,stream>>>(hs, Xb);
  cvt_wt<<<144,256,0,stream>>>(Wq, WT);
  cvt_wt<<<144,256,0,stream>>>(Wk, WT + (size_t)768*768);
  cvt_wt<<<144,256,0,stream>>>(Wv, WT + (size_t)2*768*768);
  bmask_k<<<4,256,0,stream>>>(am, bmf);
  qkv_gemm<<<dim3(48,3),256,0,stream>>>(Xb, WT, bq,bk,bv, qs,ks,vs);
  vtrans<<<dim3(16,12),256,0,stream>>>(vs, vT);
  wg_gemm<<<dim3(64,12),256,0,stream>>>(ks, qs, g, bmf, WG, od);
  rhos_k<<<12,256,0,stream>>>(od, rh);
  amat_t<<<dim3(256,12),256,0,stream>>>(WG, od, rh, Am, AmT, Tm);

  const float b1=-0.5f, b2=-0.125f, b3=-1.f/16.f, b4=-5.f/128.f, b5=-7.f/256.f;
  short* V = AmT;   // AmT dead after G2
  short* L = Tm;    // Tm dead after G3
  // G1: A2 = Am * Am^T^T  (= A^2)
  gemm_ps<0,false><<<dim3(64,12),256,0,stream>>>(Am, AmT, A2, nullptr,nullptr, 0,0,0, nullptr,nullptr);
  // G2: A3T = AmT * A2^T  (= (A^3)^T)
  gemm_ps<0,false><<<dim3(64,12),256,0,stream>>>(AmT, A2, A3T, nullptr,nullptr, 0,0,0, nullptr,nullptr);
  // G3: V = T * A3 + b3 I + b4 A + b5 A2
  gemm_ps<1,false><<<dim3(64,12),256,0,stream>>>(Tm, A3T, V, Am, A2, b3,b4,b5, nullptr,nullptr);
  // G4: L = V * A3 + I + b1 A + b2 A2   (+ fused row |L| sums and diagonal)
  gemm_ps<1,true><<<dim3(64,12),256,0,stream>>>(V, A3T, L, Am, A2, 1.0f,b1,b2, rab, dv);

  attn_k<<<dim3(8,12),256,0,stream>>>(WG, L, vT, vs, od, dv, rab, out);
}

// Round 3
// 294.160 us; speedup vs baseline: 1.3557x; 1.0839x over previous
//
#include <hip/hip_runtime.h>
#include <hip/hip_bf16.h>

typedef __attribute__((ext_vector_type(4))) float f32x4;
typedef __attribute__((ext_vector_type(8))) short s16x8;

typedef const __attribute__((address_space(1))) void* gptr_t;
typedef __attribute__((address_space(3))) void* lptr_t;

__device__ __forceinline__ short f2b(float f){ __hip_bfloat16 h=__float2bfloat16(f); return *(short*)&h; }
__device__ __forceinline__ float b2f(short s){ __hip_bfloat16 h; *(short*)&h = s; return __bfloat162float(h); }

__device__ __forceinline__ void gl_lds16(const void* g, void* l){
  __builtin_amdgcn_global_load_lds((gptr_t)g, (lptr_t)l, 16, 0, 0);
}

// ---------------- small prep kernels ----------------

__global__ __launch_bounds__(256) void cvt_x(const float* __restrict__ X, short* __restrict__ Xb){
  int i = blockIdx.x*256 + threadIdx.x;
  const float4* p = (const float4*)(X + (size_t)i*8);
  float4 a = p[0], b = p[1];
  s16x8 o;
  o[0]=f2b(a.x); o[1]=f2b(a.y); o[2]=f2b(a.z); o[3]=f2b(a.w);
  o[4]=f2b(b.x); o[5]=f2b(b.y); o[6]=f2b(b.z); o[7]=f2b(b.w);
  *(s16x8*)(Xb + (size_t)i*8) = o;
}

// W fp32 [768][768] -> WT bf16 [768][768] with WT[n][l]=W[l][n]
__global__ __launch_bounds__(256) void cvt_wt(const float* __restrict__ W, short* __restrict__ WT){
  __shared__ short tile[64][72];
  int bl = blockIdx.x % 12, bn = blockIdx.x / 12;
  int l0 = bl*64, n0 = bn*64;
  int t = threadIdx.x;
  #pragma unroll
  for (int p=0;p<4;p++){
    int lr = p*16 + (t>>4);
    int nc = (t&15)*4;
    float4 v = *(const float4*)(W + (size_t)(l0+lr)*768 + n0 + nc);
    tile[lr][nc+0]=f2b(v.x); tile[lr][nc+1]=f2b(v.y); tile[lr][nc+2]=f2b(v.z); tile[lr][nc+3]=f2b(v.w);
  }
  __syncthreads();
  #pragma unroll
  for (int p=0;p<2;p++){
    int nr = p*32 + (t>>3);
    int lc = (t&7)*8;
    s16x8 o;
    #pragma unroll
    for(int u=0;u<8;u++) o[u] = tile[lc+u][nr];
    *(s16x8*)(WT + (size_t)(n0+nr)*768 + l0 + lc) = o;
  }
}

__global__ void bmask_k(const float* __restrict__ am, float* __restrict__ bmf){
  int i = blockIdx.x*256+threadIdx.x;
  if (i<1024) bmf[i] = (am[i] >= 0.0f) ? 1.0f : 0.0f;
}

// v bf16 [1024][768] -> vT bf16 [12][64][1024]
__global__ __launch_bounds__(256) void vtrans(const short* __restrict__ vs, short* __restrict__ vT){
  __shared__ short tile[64][72];
  int h = blockIdx.y; int i0 = blockIdx.x*64;
  int t = threadIdx.x;
  #pragma unroll
  for(int p=0;p<2;p++){
    int ir = p*32 + (t>>3); int c8=(t&7)*8;
    *(s16x8*)&tile[ir][c8] = *(const s16x8*)(vs + (size_t)(i0+ir)*768 + h*64 + c8);
  }
  __syncthreads();
  #pragma unroll
  for(int p=0;p<2;p++){
    int dr = p*32 + (t>>3); int i8=(t&7)*8;
    s16x8 o;
    #pragma unroll
    for(int u=0;u<8;u++) o[u]=tile[i8+u][dr];
    *(s16x8*)(vT + ((size_t)h*64 + dr)*1024 + i0 + i8) = o;
  }
}

// ---------------- QKV projection GEMM ----------------
__global__ __launch_bounds__(256) void qkv_gemm(const short* __restrict__ Xb, const short* __restrict__ WT,
      const float* __restrict__ bq, const float* __restrict__ bk, const float* __restrict__ bv,
      short* __restrict__ qs, short* __restrict__ ks, short* __restrict__ vs){
  __shared__ short lA[128*32], lB[128*32];
  int mat = blockIdx.y;
  const short* B = WT + (size_t)mat*768*768;
  const float* bias = mat==0?bq:(mat==1?bk:bv);
  short* outp = mat==0?qs:(mat==1?ks:vs);
  float scale = mat==0 ? 0.125f : 1.0f;
  int tm = (blockIdx.x / 6)*128, tn = (blockIdx.x % 6)*128;
  int t=threadIdx.x, wave=t>>6, lane=t&63;
  int srow=t>>2, scol=(t&3)*8;
  int wm=(wave>>1)*64, wn=(wave&1)*64;
  f32x4 acc[4][4]={};
  for (int k0=0;k0<768;k0+=32){
    #pragma unroll
    for(int r=0;r<2;++r){
      gl_lds16(Xb + (size_t)(tm+srow+r*64)*768 + k0 + scol, lA + r*2048 + wave*512);
      gl_lds16(B  + (size_t)(tn+srow+r*64)*768 + k0 + scol, lB + r*2048 + wave*512);
    }
    __syncthreads();
    int krow=(lane>>4)*8, rl=lane&15;
    s16x8 af[4], bfr[4];
    #pragma unroll
    for(int m=0;m<4;m++) af[m] = *(s16x8*)&lA[(wm+m*16+rl)*32 + krow];
    #pragma unroll
    for(int n=0;n<4;n++) bfr[n] = *(s16x8*)&lB[(wn+n*16+rl)*32 + krow];
    #pragma unroll
    for(int m=0;m<4;m++)
      #pragma unroll
      for(int n=0;n<4;n++)
        acc[m][n]=__builtin_amdgcn_mfma_f32_16x16x32_bf16(af[m],bfr[n],acc[m][n],0,0,0);
    __syncthreads();
  }
  int r0 = tm + wm + (lane>>4)*4, c0 = tn + wn + (lane&15);
  #pragma unroll
  for(int m=0;m<4;m++)
    #pragma unroll
    for(int n=0;n<4;n++){
      int col = c0 + n*16; float bb = bias[col];
      #pragma unroll
      for(int r=0;r<4;r++){
        int row = r0 + m*16 + r;
        outp[(size_t)row*768 + col] = f2b((acc[m][n][r] + bb)*scale);
      }
    }
}

// ---------------- W_G = exp(K Q^T) masked, + row sums ----------------
__global__ __launch_bounds__(256) void wg_gemm(const short* __restrict__ kb, const short* __restrict__ qb,
      const int* __restrict__ g, const float* __restrict__ bmf,
      short* __restrict__ WG, float* __restrict__ od){
  __shared__ short lK[128*64], lQ[128*64];
  int h=blockIdx.y;
  int tm=(blockIdx.x>>3)*128, tn=(blockIdx.x&7)*128;
  int t=threadIdx.x, wave=t>>6, lane=t&63;
  int srow=t>>3, scol=(t&7)*8;
  int wm=(wave>>1)*64, wn=(wave&1)*64;
  #pragma unroll
  for(int r=0;r<4;++r){
    gl_lds16(kb + (size_t)(tm+srow+r*32)*768 + h*64 + scol, lK + r*2048 + wave*512);
    gl_lds16(qb + (size_t)(tn+srow+r*32)*768 + h*64 + scol, lQ + r*2048 + wave*512);
  }
  __syncthreads();
  int rl=lane&15;
  f32x4 acc[4][4]={};
  #pragma unroll
  for(int ks=0;ks<2;ks++){
    int krow=ks*32+(lane>>4)*8;
    s16x8 af[4], bfr[4];
    #pragma unroll
    for(int m=0;m<4;m++) af[m]=*(s16x8*)&lK[(wm+m*16+rl)*64+krow];
    #pragma unroll
    for(int n=0;n<4;n++) bfr[n]=*(s16x8*)&lQ[(wn+n*16+rl)*64+krow];
    #pragma unroll
    for(int m=0;m<4;m++)
      #pragma unroll
      for(int n=0;n<4;n++)
        acc[m][n]=__builtin_amdgcn_mfma_f32_16x16x32_bf16(af[m],bfr[n],acc[m][n],0,0,0);
  }
  size_t hm=(size_t)h<<20;
  int r0=tm+wm+(lane>>4)*4, c0=tn+wn+rl;
  #pragma unroll
  for(int m=0;m<4;m++){
    float rs[4]={0.f,0.f,0.f,0.f};
    #pragma unroll
    for(int n=0;n<4;n++){
      int col=c0+n*16;
      float mc = bmf[col];
      #pragma unroll
      for(int r=0;r<4;r++){
        int row=r0+m*16+r;
        float e = expf(acc[m][n][r]);
        float w = (g[(size_t)row*1024+col]>0 && bmf[row]>0.f && mc>0.f) ? e : 0.f;
        WG[hm+(size_t)row*1024+col]=f2b(w);
        rs[r]+=w;
      }
    }
    #pragma unroll
    for(int r=0;r<4;r++){
      float s=rs[r];
      #pragma unroll
      for(int off=1;off<16;off<<=1) s+=__shfl_xor(s,off);
      if(rl==0) atomicAdd(&od[(h<<10)+r0+m*16+r], s);
    }
  }
}

__global__ void rhos_k(const float* __restrict__ od, float* __restrict__ rhos){
  __shared__ float red[256];
  int h = blockIdx.x, t = threadIdx.x;
  float m = -1e30f;
  for (int i=t;i<1024;i+=256) m = fmaxf(m, od[(h<<10)+i]);
  red[t]=m; __syncthreads();
  for(int s=128;s>0;s>>=1){ if(t<s) red[t]=fmaxf(red[t],red[t+s]); __syncthreads(); }
  if(t==0) rhos[h]=red[0];
}

// Am = (WG + diag(rho-od))/rho ; AmT = Am^T ; T = b7*Am + b6*I  (one tiled pass)
__global__ __launch_bounds__(256) void amat_t(const short* __restrict__ WG, const float* __restrict__ od,
      const float* __restrict__ rhos, short* __restrict__ Am, short* __restrict__ AmT,
      short* __restrict__ T){
  __shared__ short tile[64][72];
  const float b7 = -33.f/2048.f, b6 = -21.f/1024.f;
  int h = blockIdx.y; int bx = blockIdx.x;
  int rb = bx >> 4, cb = bx & 15;
  int r0 = rb*64, c0 = cb*64;
  float rho = rhos[h]; float inv = 1.0f/fmaxf(rho,1e-30f);
  size_t hm = (size_t)h<<20;
  int t = threadIdx.x;
  #pragma unroll
  for(int p=0;p<2;p++){
    int r = p*32 + (t>>3); int c8 = (t&7)*8;
    size_t base = hm + (size_t)(r0+r)*1024 + c0 + c8;
    s16x8 w = *(const s16x8*)(WG + base);
    s16x8 oa, ot;
    float dadd = (rho - od[(h<<10)+r0+r])*inv;
    #pragma unroll
    for(int u=0;u<8;u++){
      bool dg = (rb==cb) && ((c8+u)==r);
      float a = b2f(w[u])*inv + (dg ? dadd : 0.f);
      oa[u]=f2b(a);
      ot[u]=f2b(b7*a + (dg ? b6 : 0.f));
      tile[r][c8+u]=oa[u];
    }
    *(s16x8*)(Am+base)=oa; *(s16x8*)(T+base)=ot;
  }
  __syncthreads();
  #pragma unroll
  for(int p=0;p<2;p++){
    int c = p*32 + (t>>3); int r8 = (t&7)*8;
    s16x8 o;
    #pragma unroll
    for(int u=0;u<8;u++) o[u]=tile[r8+u][c];
    *(s16x8*)(AmT + hm + (size_t)(c0+c)*1024 + r0 + r8) = o;
  }
}

// ---------------- big GEMMs: D = X*Y^T per head, 128^2 tile, XCD-chunked swizzle ----
// grid = 768 1-D blocks (= 12 heads x 64 tiles), 768 % 8 == 0 -> simple swizzle bijective.
#define GEMM_PROLOG \
  __shared__ short lA[128*32], lB[128*32]; \
  int wg = (blockIdx.x & 7)*96 + (blockIdx.x >> 3); \
  int h = wg >> 6; int tile = wg & 63; \
  int tm=(tile>>3)*128, tn=(tile&7)*128; \
  size_t hm=(size_t)h<<20; \
  int t=threadIdx.x, wave=t>>6, lane=t&63; \
  int srow=t>>2, scol=(t&3)*8; \
  int wm=(wave>>1)*64, wn=(wave&1)*64; \
  f32x4 acc[4][4]={}; \
  for(int k0=0;k0<1024;k0+=32){ \
    _Pragma("unroll") \
    for(int r=0;r<2;++r){ \
      gl_lds16(A + hm + (size_t)(tm+srow+r*64)*1024 + k0 + scol, lA + r*2048 + wave*512); \
      gl_lds16(B + hm + (size_t)(tn+srow+r*64)*1024 + k0 + scol, lB + r*2048 + wave*512); \
    } \
    __syncthreads(); \
    int krow=(lane>>4)*8, rl=lane&15; \
    s16x8 af[4], bfr[4]; \
    _Pragma("unroll") \
    for(int m=0;m<4;m++) af[m]=*(s16x8*)&lA[(wm+m*16+rl)*32+krow]; \
    _Pragma("unroll") \
    for(int n=0;n<4;n++) bfr[n]=*(s16x8*)&lB[(wn+n*16+rl)*32+krow]; \
    _Pragma("unroll") \
    for(int m=0;m<4;m++) \
      _Pragma("unroll") \
      for(int n=0;n<4;n++) \
        acc[m][n]=__builtin_amdgcn_mfma_f32_16x16x32_bf16(af[m],bfr[n],acc[m][n],0,0,0); \
    __syncthreads(); \
  } \
  int r0=tm+wm+(lane>>4)*4, c0=tn+wn+(lane&15);

__global__ __launch_bounds__(256) void gemm_plain(const short* __restrict__ A, const short* __restrict__ B,
      short* __restrict__ D){
  GEMM_PROLOG
  #pragma unroll
  for(int m=0;m<4;m++)
    #pragma unroll
    for(int n=0;n<4;n++){
      int col=c0+n*16;
      #pragma unroll
      for(int r=0;r<4;r++){
        int row=r0+m*16+r;
        D[hm + (size_t)row*1024 + col]=f2b(acc[m][n][r]);
      }
    }
}

__global__ __launch_bounds__(256) void gemm_epi(const short* __restrict__ A, const short* __restrict__ B,
      short* __restrict__ D, const short* __restrict__ E1, const short* __restrict__ E2,
      float c0c, float cA, float cB){
  GEMM_PROLOG
  #pragma unroll
  for(int m=0;m<4;m++)
    #pragma unroll
    for(int n=0;n<4;n++){
      int col=c0+n*16;
      #pragma unroll
      for(int r=0;r<4;r++){
        int row=r0+m*16+r;
        size_t e = hm + (size_t)row*1024 + col;
        float v = acc[m][n][r] + cA*b2f(E1[e]) + cB*b2f(E2[e]);
        if(row==col) v += c0c;
        D[e]=f2b(v);
      }
    }
}

__global__ __launch_bounds__(256) void gemm_epi_stat(const short* __restrict__ A, const short* __restrict__ B,
      short* __restrict__ D, const short* __restrict__ E1, const short* __restrict__ E2,
      float c0c, float cA, float cB, float* __restrict__ rowabs, float* __restrict__ dvp){
  GEMM_PROLOG
  int rl = lane&15;
  #pragma unroll
  for(int m=0;m<4;m++){
    float rs[4]={0.f,0.f,0.f,0.f};
    #pragma unroll
    for(int n=0;n<4;n++){
      int col=c0+n*16;
      #pragma unroll
      for(int r=0;r<4;r++){
        int row=r0+m*16+r;
        size_t e = hm + (size_t)row*1024 + col;
        float v = acc[m][n][r] + cA*b2f(E1[e]) + cB*b2f(E2[e]);
        if(row==col){ v += c0c; dvp[(h<<10)+row] = v; }
        rs[r] += fabsf(v);
        D[e]=f2b(v);
      }
    }
    #pragma unroll
    for(int r=0;r<4;r++){
      float s=rs[r];
      #pragma unroll
      for(int off=1;off<16;off<<=1) s+=__shfl_xor(s,off);
      if(rl==0) atomicAdd(&rowabs[(h<<10)+r0+m*16+r], s);
    }
  }
}

// ---------------- final: attn = .8*(WG/od)@v + .2*(d_i v_i - L@v)/r_i ----------------
__global__ __launch_bounds__(256) void attn_k(const short* __restrict__ WG, const short* __restrict__ L,
    const short* __restrict__ vT, const short* __restrict__ vs,
    const float* __restrict__ od, const float* __restrict__ dv, const float* __restrict__ rowabs,
    float* __restrict__ out){
  __shared__ short lW[128*32], lL[128*32], lV[64*32];
  int h=blockIdx.y, tm=blockIdx.x*128;
  size_t hm=(size_t)h<<20;
  int t=threadIdx.x, wave=t>>6, lane=t&63;
  int srow=t>>2, scol=(t&3)*8;
  f32x4 a1[2][4]={}, a2[2][4]={};
  for(int j0=0;j0<1024;j0+=32){
    #pragma unroll
    for(int r=0;r<2;++r){
      gl_lds16(WG + hm + (size_t)(tm+srow+r*64)*1024 + j0 + scol, lW + r*2048 + wave*512);
      gl_lds16(L  + hm + (size_t)(tm+srow+r*64)*1024 + j0 + scol, lL + r*2048 + wave*512);
    }
    gl_lds16(vT + ((size_t)h*64 + srow)*1024 + j0 + scol, lV + wave*512);
    __syncthreads();
    int krow=(lane>>4)*8, rl=lane&15;
    s16x8 fw[2], fl[2], fv[4];
    #pragma unroll
    for(int m=0;m<2;m++){
      fw[m]=*(s16x8*)&lW[(wave*32+m*16+rl)*32+krow];
      fl[m]=*(s16x8*)&lL[(wave*32+m*16+rl)*32+krow];
    }
    #pragma unroll
    for(int n=0;n<4;n++) fv[n]=*(s16x8*)&lV[(n*16+rl)*32+krow];
    #pragma unroll
    for(int m=0;m<2;m++)
      #pragma unroll
      for(int n=0;n<4;n++){
        a1[m][n]=__builtin_amdgcn_mfma_f32_16x16x32_bf16(fw[m],fv[n],a1[m][n],0,0,0);
        a2[m][n]=__builtin_amdgcn_mfma_f32_16x16x32_bf16(fl[m],fv[n],a2[m][n],0,0,0);
      }
    __syncthreads();
  }
  #pragma unroll
  for(int m=0;m<2;m++)
    #pragma unroll
    for(int r=0;r<4;r++){
      int row = tm + wave*32 + m*16 + (lane>>4)*4 + r;
      float invod = 1.0f/fmaxf(od[(h<<10)+row], 1e-12f);
      float dvi = dv[(h<<10)+row];
      float ivr = 1.0f/fmaxf(rowabs[(h<<10)+row] - fabsf(dvi), 1e-12f);
      #pragma unroll
      for(int n=0;n<4;n++){
        int d = n*16 + (lane&15);
        float vv = b2f(vs[(size_t)row*768 + h*64 + d]);
        out[(((size_t)h<<10)+row)*64 + d] = 0.8f*a1[m][n][r]*invod + 0.2f*(dvi*vv - a2[m][n][r])*ivr;
      }
    }
}

// ---------------- launch ----------------
extern "C" void kernel_launch(void* const* d_in, const int* in_sizes, int n_in,
                              void* d_out, int out_size, void* d_ws, size_t ws_size,
                              hipStream_t stream){
  const float* hs = (const float*)d_in[0];
  const float* Wq = (const float*)d_in[1];
  const float* bq = (const float*)d_in[2];
  const float* Wk = (const float*)d_in[3];
  const float* bk = (const float*)d_in[4];
  const float* Wv = (const float*)d_in[5];
  const float* bv = (const float*)d_in[6];
  const int*   g  = (const int*)d_in[7];
  const float* am = (const float*)d_in[8];
  float* out = (float*)d_out;

  char* w = (char*)d_ws;
  auto alloc=[&](size_t bytes)->char*{ char* p=w; w += (bytes+255)&~(size_t)255; return p; };
  short* Xb  = (short*)alloc((size_t)1024*768*2);
  short* WT  = (short*)alloc((size_t)3*768*768*2);
  short* qs  = (short*)alloc((size_t)1024*768*2);
  short* ks  = (short*)alloc((size_t)1024*768*2);
  short* vs  = (short*)alloc((size_t)1024*768*2);
  short* vT  = (short*)alloc((size_t)12*64*1024*2);
  short* WG  = (short*)alloc((size_t)12*1024*1024*2);
  short* Am  = (short*)alloc((size_t)12*1024*1024*2);
  short* AmT = (short*)alloc((size_t)12*1024*1024*2);  // later reused as V
  short* Tm  = (short*)alloc((size_t)12*1024*1024*2);  // later reused as L
  short* A2  = (short*)alloc((size_t)12*1024*1024*2);
  short* A3T = (short*)alloc((size_t)12*1024*1024*2);
  float* od  = (float*)alloc((size_t)12*1024*4);
  float* rh  = (float*)alloc((size_t)64*4);
  float* bmf = (float*)alloc((size_t)1024*4);
  float* dv  = (float*)alloc((size_t)12*1024*4);
  float* rab = (float*)alloc((size_t)12*1024*4);

  hipMemsetAsync(od,  0, (size_t)12*1024*4, stream);
  hipMemsetAsync(rab, 0, (size_t)12*1024*4, stream);

  cvt_x<<<384,256,0,stream>>>(hs, Xb);
  cvt_wt<<<144,256,0,stream>>>(Wq, WT);
  cvt_wt<<<144,256,0,stream>>>(Wk, WT + (size_t)768*768);
  cvt_wt<<<144,256,0,stream>>>(Wv, WT + (size_t)2*768*768);
  bmask_k<<<4,256,0,stream>>>(am, bmf);
  qkv_gemm<<<dim3(48,3),256,0,stream>>>(Xb, WT, bq,bk,bv, qs,ks,vs);
  vtrans<<<dim3(16,12),256,0,stream>>>(vs, vT);
  wg_gemm<<<dim3(64,12),256,0,stream>>>(ks, qs, g, bmf, WG, od);
  rhos_k<<<12,256,0,stream>>>(od, rh);
  amat_t<<<dim3(256,12),256,0,stream>>>(WG, od, rh, Am, AmT, Tm);

  const float b1=-0.5f, b2=-0.125f, b3=-1.f/16.f, b4=-5.f/128.f, b5=-7.f/256.f;
  short* V = AmT;   // AmT dead after G2
  short* L = Tm;    // Tm dead after G3
  // G1: A2 = Am * AmT^T (= A^2)
  gemm_plain<<<768,256,0,stream>>>(Am, AmT, A2);
  // G2: A3T = AmT * A2^T (= (A^3)^T)
  gemm_plain<<<768,256,0,stream>>>(AmT, A2, A3T);
  // G3: V = T * A3 + b3 I + b4 A + b5 A2
  gemm_epi<<<768,256,0,stream>>>(Tm, A3T, V, Am, A2, b3,b4,b5);
  // G4: L = V * A3 + I + b1 A + b2 A2   (+ fused row |L| sums and diagonal)
  gemm_epi_stat<<<768,256,0,stream>>>(V, A3T, L, Am, A2, 1.0f,b1,b2, rab, dv);

  attn_k<<<dim3(8,12),256,0,stream>>>(WG, L, vT, vs, od, dv, rab, out);
}

// Round 4
// 292.874 us; speedup vs baseline: 1.3616x; 1.0044x over previous
//
#include <hip/hip_runtime.h>
#include <hip/hip_bf16.h>

typedef __attribute__((ext_vector_type(4))) float f32x4;
typedef __attribute__((ext_vector_type(8))) short s16x8;

typedef const __attribute__((address_space(1))) void* gptr_t;
typedef __attribute__((address_space(3))) void* lptr_t;

__device__ __forceinline__ short f2b(float f){ __hip_bfloat16 h=__float2bfloat16(f); return *(short*)&h; }
__device__ __forceinline__ float b2f(short s){ __hip_bfloat16 h; *(short*)&h = s; return __bfloat162float(h); }

__device__ __forceinline__ void gl_lds16(const void* g, void* l){
  __builtin_amdgcn_global_load_lds((gptr_t)g, (lptr_t)l, 16, 0, 0);
}

// ---------------- small prep kernels ----------------

__global__ __launch_bounds__(256) void cvt_x(const float* __restrict__ X, short* __restrict__ Xb){
  int i = blockIdx.x*256 + threadIdx.x;
  const float4* p = (const float4*)(X + (size_t)i*8);
  float4 a = p[0], b = p[1];
  s16x8 o;
  o[0]=f2b(a.x); o[1]=f2b(a.y); o[2]=f2b(a.z); o[3]=f2b(a.w);
  o[4]=f2b(b.x); o[5]=f2b(b.y); o[6]=f2b(b.z); o[7]=f2b(b.w);
  *(s16x8*)(Xb + (size_t)i*8) = o;
}

__global__ __launch_bounds__(256) void cvt_wt(const float* __restrict__ W, short* __restrict__ WT){
  __shared__ short tile[64][72];
  int bl = blockIdx.x % 12, bn = blockIdx.x / 12;
  int l0 = bl*64, n0 = bn*64;
  int t = threadIdx.x;
  #pragma unroll
  for (int p=0;p<4;p++){
    int lr = p*16 + (t>>4);
    int nc = (t&15)*4;
    float4 v = *(const float4*)(W + (size_t)(l0+lr)*768 + n0 + nc);
    tile[lr][nc+0]=f2b(v.x); tile[lr][nc+1]=f2b(v.y); tile[lr][nc+2]=f2b(v.z); tile[lr][nc+3]=f2b(v.w);
  }
  __syncthreads();
  #pragma unroll
  for (int p=0;p<2;p++){
    int nr = p*32 + (t>>3);
    int lc = (t&7)*8;
    s16x8 o;
    #pragma unroll
    for(int u=0;u<8;u++) o[u] = tile[lc+u][nr];
    *(s16x8*)(WT + (size_t)(n0+nr)*768 + l0 + lc) = o;
  }
}

__global__ void bmask_k(const float* __restrict__ am, float* __restrict__ bmf){
  int i = blockIdx.x*256+threadIdx.x;
  if (i<1024) bmf[i] = (am[i] >= 0.0f) ? 1.0f : 0.0f;
}

__global__ __launch_bounds__(256) void vtrans(const short* __restrict__ vs, short* __restrict__ vT){
  __shared__ short tile[64][72];
  int h = blockIdx.y; int i0 = blockIdx.x*64;
  int t = threadIdx.x;
  #pragma unroll
  for(int p=0;p<2;p++){
    int ir = p*32 + (t>>3); int c8=(t&7)*8;
    *(s16x8*)&tile[ir][c8] = *(const s16x8*)(vs + (size_t)(i0+ir)*768 + h*64 + c8);
  }
  __syncthreads();
  #pragma unroll
  for(int p=0;p<2;p++){
    int dr = p*32 + (t>>3); int i8=(t&7)*8;
    s16x8 o;
    #pragma unroll
    for(int u=0;u<8;u++) o[u]=tile[i8+u][dr];
    *(s16x8*)(vT + ((size_t)h*64 + dr)*1024 + i0 + i8) = o;
  }
}

// ---------------- QKV projection GEMM ----------------
__global__ __launch_bounds__(256) void qkv_gemm(const short* __restrict__ Xb, const short* __restrict__ WT,
      const float* __restrict__ bq, const float* __restrict__ bk, const float* __restrict__ bv,
      short* __restrict__ qs, short* __restrict__ ks, short* __restrict__ vs){
  __shared__ short lA[128*32], lB[128*32];
  int mat = blockIdx.y;
  const short* B = WT + (size_t)mat*768*768;
  const float* bias = mat==0?bq:(mat==1?bk:bv);
  short* outp = mat==0?qs:(mat==1?ks:vs);
  float scale = mat==0 ? 0.125f : 1.0f;
  int tm = (blockIdx.x / 6)*128, tn = (blockIdx.x % 6)*128;
  int t=threadIdx.x, wave=t>>6, lane=t&63;
  int srow=t>>2, scol=(t&3)*8;
  int wm=(wave>>1)*64, wn=(wave&1)*64;
  f32x4 acc[4][4]={};
  for (int k0=0;k0<768;k0+=32){
    #pragma unroll
    for(int r=0;r<2;++r){
      gl_lds16(Xb + (size_t)(tm+srow+r*64)*768 + k0 + scol, lA + r*2048 + wave*512);
      gl_lds16(B  + (size_t)(tn+srow+r*64)*768 + k0 + scol, lB + r*2048 + wave*512);
    }
    __syncthreads();
    int krow=(lane>>4)*8, rl=lane&15;
    s16x8 af[4], bfr[4];
    #pragma unroll
    for(int m=0;m<4;m++) af[m] = *(s16x8*)&lA[(wm+m*16+rl)*32 + krow];
    #pragma unroll
    for(int n=0;n<4;n++) bfr[n] = *(s16x8*)&lB[(wn+n*16+rl)*32 + krow];
    #pragma unroll
    for(int m=0;m<4;m++)
      #pragma unroll
      for(int n=0;n<4;n++)
        acc[m][n]=__builtin_amdgcn_mfma_f32_16x16x32_bf16(af[m],bfr[n],acc[m][n],0,0,0);
    __syncthreads();
  }
  int r0 = tm + wm + (lane>>4)*4, c0 = tn + wn + (lane&15);
  #pragma unroll
  for(int m=0;m<4;m++)
    #pragma unroll
    for(int n=0;n<4;n++){
      int col = c0 + n*16; float bb = bias[col];
      #pragma unroll
      for(int r=0;r<4;r++){
        int row = r0 + m*16 + r;
        outp[(size_t)row*768 + col] = f2b((acc[m][n][r] + bb)*scale);
      }
    }
}

// ---------------- W_G = exp(K Q^T) masked, + row sums ----------------
__global__ __launch_bounds__(256) void wg_gemm(const short* __restrict__ kb, const short* __restrict__ qb,
      const int* __restrict__ g, const float* __restrict__ bmf,
      short* __restrict__ WG, float* __restrict__ od){
  __shared__ short lK[128*64], lQ[128*64];
  int h=blockIdx.y;
  int tm=(blockIdx.x>>3)*128, tn=(blockIdx.x&7)*128;
  int t=threadIdx.x, wave=t>>6, lane=t&63;
  int srow=t>>3, scol=(t&7)*8;
  int wm=(wave>>1)*64, wn=(wave&1)*64;
  #pragma unroll
  for(int r=0;r<4;++r){
    gl_lds16(kb + (size_t)(tm+srow+r*32)*768 + h*64 + scol, lK + r*2048 + wave*512);
    gl_lds16(qb + (size_t)(tn+srow+r*32)*768 + h*64 + scol, lQ + r*2048 + wave*512);
  }
  __syncthreads();
  int rl=lane&15;
  f32x4 acc[4][4]={};
  #pragma unroll
  for(int ks=0;ks<2;ks++){
    int krow=ks*32+(lane>>4)*8;
    s16x8 af[4], bfr[4];
    #pragma unroll
    for(int m=0;m<4;m++) af[m]=*(s16x8*)&lK[(wm+m*16+rl)*64+krow];
    #pragma unroll
    for(int n=0;n<4;n++) bfr[n]=*(s16x8*)&lQ[(wn+n*16+rl)*64+krow];
    #pragma unroll
    for(int m=0;m<4;m++)
      #pragma unroll
      for(int n=0;n<4;n++)
        acc[m][n]=__builtin_amdgcn_mfma_f32_16x16x32_bf16(af[m],bfr[n],acc[m][n],0,0,0);
  }
  size_t hm=(size_t)h<<20;
  int r0=tm+wm+(lane>>4)*4, c0=tn+wn+rl;
  #pragma unroll
  for(int m=0;m<4;m++){
    float rs[4]={0.f,0.f,0.f,0.f};
    #pragma unroll
    for(int n=0;n<4;n++){
      int col=c0+n*16;
      float mc = bmf[col];
      #pragma unroll
      for(int r=0;r<4;r++){
        int row=r0+m*16+r;
        float e = expf(acc[m][n][r]);
        float w = (g[(size_t)row*1024+col]>0 && bmf[row]>0.f && mc>0.f) ? e : 0.f;
        WG[hm+(size_t)row*1024+col]=f2b(w);
        rs[r]+=w;
      }
    }
    #pragma unroll
    for(int r=0;r<4;r++){
      float s=rs[r];
      #pragma unroll
      for(int off=1;off<16;off<<=1) s+=__shfl_xor(s,off);
      if(rl==0) atomicAdd(&od[(h<<10)+r0+m*16+r], s);
    }
  }
}

__global__ void rhos_k(const float* __restrict__ od, float* __restrict__ rhos){
  __shared__ float red[256];
  int h = blockIdx.x, t = threadIdx.x;
  float m = -1e30f;
  for (int i=t;i<1024;i+=256) m = fmaxf(m, od[(h<<10)+i]);
  red[t]=m; __syncthreads();
  for(int s=128;s>0;s>>=1){ if(t<s) red[t]=fmaxf(red[t],red[t+s]); __syncthreads(); }
  if(t==0) rhos[h]=red[0];
}

// Am = (WG + diag(rho-od))/rho ; AmT = Am^T ; T = b7*Am + b6*I
__global__ __launch_bounds__(256) void amat_t(const short* __restrict__ WG, const float* __restrict__ od,
      const float* __restrict__ rhos, short* __restrict__ Am, short* __restrict__ AmT,
      short* __restrict__ T){
  __shared__ short tile[64][72];
  const float b7 = -33.f/2048.f, b6 = -21.f/1024.f;
  int h = blockIdx.y; int bx = blockIdx.x;
  int rb = bx >> 4, cb = bx & 15;
  int r0 = rb*64, c0 = cb*64;
  float rho = rhos[h]; float inv = 1.0f/fmaxf(rho,1e-30f);
  size_t hm = (size_t)h<<20;
  int t = threadIdx.x;
  #pragma unroll
  for(int p=0;p<2;p++){
    int r = p*32 + (t>>3); int c8 = (t&7)*8;
    size_t base = hm + (size_t)(r0+r)*1024 + c0 + c8;
    s16x8 w = *(const s16x8*)(WG + base);
    s16x8 oa, ot;
    float dadd = (rho - od[(h<<10)+r0+r])*inv;
    #pragma unroll
    for(int u=0;u<8;u++){
      bool dg = (rb==cb) && ((c8+u)==r);
      float a = b2f(w[u])*inv + (dg ? dadd : 0.f);
      oa[u]=f2b(a);
      ot[u]=f2b(b7*a + (dg ? b6 : 0.f));
      tile[r][c8+u]=oa[u];
    }
    *(s16x8*)(Am+base)=oa; *(s16x8*)(T+base)=ot;
  }
  __syncthreads();
  #pragma unroll
  for(int p=0;p<2;p++){
    int c = p*32 + (t>>3); int r8 = (t&7)*8;
    s16x8 o;
    #pragma unroll
    for(int u=0;u<8;u++) o[u]=tile[r8+u][c];
    *(s16x8*)(AmT + hm + (size_t)(c0+c)*1024 + r0 + r8) = o;
  }
}

// ============ 256^2 8-phase GEMM (T2 swizzle + T3/T4 counted vmcnt + T5 setprio) ============
// D = X*Y^T per head. 12 heads x 16 tiles = 192 blocks, 512 threads (8 waves, 2Mx4N).
// K-tile = 64, split in two K-halves (units). LDS 128 KiB: [dbuf][unit A0,A1,B0,B1][256 rows x 32 bf16].
// Swizzle: byte ^= (((row^(row>>2))&3)<<4)  -- involution on bits 4-5, row-invariant.

#define PH(MH, KS, D_, DOST, U, KT, DN, WN) { \
  if (DOST) { \
    _Pragma("unroll") \
    for (int r_=0;r_<2;r_++){ \
      const short* sp_ = ((U)<2 ? Ag : Bg) + (size_t)(((U)<2 ? tm : tn) + rS[r_])*1024 + (KT)*64 + ((U)&1)*32 + cS[r_]; \
      gl_lds16(sp_, &lds[DN][U][r_*4096 + wave*512]); \
    } \
  } \
  const char* au_ = (const char*)&lds[D_][KS][0]; \
  const char* bu_ = (const char*)&lds[D_][2+(KS)][0]; \
  s16x8 af_[4], bf_[4]; \
  _Pragma("unroll") \
  for (int m_=0;m_<4;m_++) af_[m_] = *(const s16x8*)(au_ + aoff[MH][m_]); \
  _Pragma("unroll") \
  for (int n_=0;n_<4;n_++) bf_[n_] = *(const s16x8*)(bu_ + boff[n_]); \
  __builtin_amdgcn_s_barrier(); \
  asm volatile("s_waitcnt lgkmcnt(0)" ::: "memory"); \
  __builtin_amdgcn_sched_barrier(0); \
  __builtin_amdgcn_s_setprio(1); \
  _Pragma("unroll") \
  for (int m_=0;m_<4;m_++) \
    _Pragma("unroll") \
    for (int n_=0;n_<4;n_++) \
      acc[(MH)*4+m_][n_] = __builtin_amdgcn_mfma_f32_16x16x32_bf16(af_[m_], bf_[n_], acc[(MH)*4+m_][n_], 0,0,0); \
  __builtin_amdgcn_s_setprio(0); \
  if ((WN)==4) { asm volatile("s_waitcnt vmcnt(4)" ::: "memory"); } \
  else if ((WN)==0) { asm volatile("s_waitcnt vmcnt(0)" ::: "memory"); } \
  __builtin_amdgcn_s_barrier(); }

#define GEMM8P_PROLOG \
  __shared__ short lds[2][4][8192]; \
  int wg = ((int)blockIdx.x & 7)*24 + ((int)blockIdx.x >> 3); \
  int h = wg >> 4; int tile_ = wg & 15; \
  int tm = (tile_>>2)*256, tn = (tile_&3)*256; \
  size_t hm = (size_t)h<<20; \
  const short* Ag = A + hm; const short* Bg = B + hm; \
  int tid = threadIdx.x, wave = tid>>6, lane = tid&63; \
  int wm = wave>>2, wn = wave&3; \
  int rl = lane & 15; \
  int rS[2], cS[2]; \
  _Pragma("unroll") \
  for (int r_=0;r_<2;r_++){ \
    int alpha = (r_*512 + tid)*16; int row = alpha>>6; int q = (row ^ (row>>2)) & 3; \
    rS[r_] = row; cS[r_] = (((alpha&63) ^ (q<<4))>>1); \
  } \
  int aoff[2][4], boff[4]; \
  { int koff = ((lane>>4)&3)*16; \
    _Pragma("unroll") \
    for (int mh_=0;mh_<2;mh_++) \
      _Pragma("unroll") \
      for (int m_=0;m_<4;m_++){ int rho = wm*128 + mh_*64 + m_*16 + rl; int lin = rho*64 + koff; \
        aoff[mh_][m_] = lin ^ (((rho^(rho>>2))&3)<<4); } \
    _Pragma("unroll") \
    for (int n_=0;n_<4;n_++){ int rho = wn*64 + n_*16 + rl; int lin = rho*64 + koff; \
      boff[n_] = lin ^ (((rho^(rho>>2))&3)<<4); } \
  } \
  f32x4 acc[8][4] = {}; \
  /* prologue: stage tile 0 into dbuf 0 */ \
  _Pragma("unroll") \
  for (int u_=0;u_<4;u_++){ \
    _Pragma("unroll") \
    for (int r_=0;r_<2;r_++){ \
      const short* sp_ = (u_<2 ? Ag : Bg) + (size_t)((u_<2 ? tm : tn) + rS[r_])*1024 + (u_&1)*32 + cS[r_]; \
      gl_lds16(sp_, &lds[0][u_][r_*4096 + wave*512]); \
    } \
  } \
  asm volatile("s_waitcnt vmcnt(4)" ::: "memory"); \
  __builtin_amdgcn_s_barrier(); \
  _Pragma("unroll 1") \
  for (int t_=0; t_<15; ++t_){ \
    const int d_ = t_&1, dn_ = d_^1; \
    PH(0,0, d_, 1, 0, t_+1, dn_, -1) \
    PH(1,0, d_, 1, 1, t_+1, dn_, 4) \
    PH(0,1, d_, 1, 2, t_+1, dn_, -1) \
    PH(1,1, d_, 1, 3, t_+1, dn_, 4) \
  } \
  PH(0,0, 1, 0, 0, 0, 0, -1) \
  PH(1,0, 1, 0, 0, 0, 0, 0) \
  PH(0,1, 1, 0, 0, 0, 0, -1) \
  PH(1,1, 1, 0, 0, 0, 0, -1) \
  int rb = tm + wm*128 + ((lane>>4)&3)*4; \
  int cb = tn + wn*64 + rl;

__global__ __launch_bounds__(512,2) void gemm8p_plain(const short* __restrict__ A, const short* __restrict__ B,
      short* __restrict__ D){
  GEMM8P_PROLOG
  short* Dg = D + hm;
  #pragma unroll
  for (int f=0;f<8;f++)
    #pragma unroll
    for (int n=0;n<4;n++){
      int col = cb + n*16;
      #pragma unroll
      for (int rr=0;rr<4;rr++)
        Dg[(size_t)(rb + f*16 + rr)*1024 + col] = f2b(acc[f][n][rr]);
    }
}

__global__ __launch_bounds__(512,2) void gemm8p_epi(const short* __restrict__ A, const short* __restrict__ B,
      short* __restrict__ D, const short* __restrict__ E1, const short* __restrict__ E2,
      float c0c, float cA, float cB){
  GEMM8P_PROLOG
  short* Dg = D + hm;
  const short* E1g = E1 + hm; const short* E2g = E2 + hm;
  #pragma unroll
  for (int f=0;f<8;f++)
    #pragma unroll
    for (int n=0;n<4;n++){
      int col = cb + n*16;
      #pragma unroll
      for (int rr=0;rr<4;rr++){
        int row = rb + f*16 + rr;
        size_t e = (size_t)row*1024 + col;
        float v = acc[f][n][rr] + cA*b2f(E1g[e]) + cB*b2f(E2g[e]);
        if (row==col) v += c0c;
        Dg[e] = f2b(v);
      }
    }
}

__global__ __launch_bounds__(512,2) void gemm8p_epi_stat(const short* __restrict__ A, const short* __restrict__ B,
      short* __restrict__ D, const short* __restrict__ E1, const short* __restrict__ E2,
      float c0c, float cA, float cB, float* __restrict__ rowabs, float* __restrict__ dvp){
  GEMM8P_PROLOG
  short* Dg = D + hm;
  const short* E1g = E1 + hm; const short* E2g = E2 + hm;
  #pragma unroll
  for (int f=0;f<8;f++){
    float rs[4]={0.f,0.f,0.f,0.f};
    #pragma unroll
    for (int n=0;n<4;n++){
      int col = cb + n*16;
      #pragma unroll
      for (int rr=0;rr<4;rr++){
        int row = rb + f*16 + rr;
        size_t e = (size_t)row*1024 + col;
        float v = acc[f][n][rr] + cA*b2f(E1g[e]) + cB*b2f(E2g[e]);
        if (row==col){ v += c0c; dvp[(h<<10)+row] = v; }
        rs[rr] += fabsf(v);
        Dg[e] = f2b(v);
      }
    }
    #pragma unroll
    for (int rr=0;rr<4;rr++){
      float s=rs[rr];
      #pragma unroll
      for(int off=1;off<16;off<<=1) s+=__shfl_xor(s,off);
      if(rl==0) atomicAdd(&rowabs[(h<<10)+rb+f*16+rr], s);
    }
  }
}

// ---------------- final: attn = .8*(WG/od)@v + .2*(d_i v_i - L@v)/r_i ----------------
__global__ __launch_bounds__(256) void attn_k(const short* __restrict__ WG, const short* __restrict__ L,
    const short* __restrict__ vT, const short* __restrict__ vs,
    const float* __restrict__ od, const float* __restrict__ dv, const float* __restrict__ rowabs,
    float* __restrict__ out){
  __shared__ short lW[128*32], lL[128*32], lV[64*32];
  int h=blockIdx.y, tm=blockIdx.x*128;
  size_t hm=(size_t)h<<20;
  int t=threadIdx.x, wave=t>>6, lane=t&63;
  int srow=t>>2, scol=(t&3)*8;
  f32x4 a1[2][4]={}, a2[2][4]={};
  for(int j0=0;j0<1024;j0+=32){
    #pragma unroll
    for(int r=0;r<2;++r){
      gl_lds16(WG + hm + (size_t)(tm+srow+r*64)*1024 + j0 + scol, lW + r*2048 + wave*512);
      gl_lds16(L  + hm + (size_t)(tm+srow+r*64)*1024 + j0 + scol, lL + r*2048 + wave*512);
    }
    gl_lds16(vT + ((size_t)h*64 + srow)*1024 + j0 + scol, lV + wave*512);
    __syncthreads();
    int krow=(lane>>4)*8, rl=lane&15;
    s16x8 fw[2], fl[2], fv[4];
    #pragma unroll
    for(int m=0;m<2;m++){
      fw[m]=*(s16x8*)&lW[(wave*32+m*16+rl)*32+krow];
      fl[m]=*(s16x8*)&lL[(wave*32+m*16+rl)*32+krow];
    }
    #pragma unroll
    for(int n=0;n<4;n++) fv[n]=*(s16x8*)&lV[(n*16+rl)*32+krow];
    #pragma unroll
    for(int m=0;m<2;m++)
      #pragma unroll
      for(int n=0;n<4;n++){
        a1[m][n]=__builtin_amdgcn_mfma_f32_16x16x32_bf16(fw[m],fv[n],a1[m][n],0,0,0);
        a2[m][n]=__builtin_amdgcn_mfma_f32_16x16x32_bf16(fl[m],fv[n],a2[m][n],0,0,0);
      }
    __syncthreads();
  }
  #pragma unroll
  for(int m=0;m<2;m++)
    #pragma unroll
    for(int r=0;r<4;r++){
      int row = tm + wave*32 + m*16 + (lane>>4)*4 + r;
      float invod = 1.0f/fmaxf(od[(h<<10)+row], 1e-12f);
      float dvi = dv[(h<<10)+row];
      float ivr = 1.0f/fmaxf(rowabs[(h<<10)+row] - fabsf(dvi), 1e-12f);
      #pragma unroll
      for(int n=0;n<4;n++){
        int d = n*16 + (lane&15);
        float vv = b2f(vs[(size_t)row*768 + h*64 + d]);
        out[(((size_t)h<<10)+row)*64 + d] = 0.8f*a1[m][n][r]*invod + 0.2f*(dvi*vv - a2[m][n][r])*ivr;
      }
    }
}

// ---------------- launch ----------------
extern "C" void kernel_launch(void* const* d_in, const int* in_sizes, int n_in,
                              void* d_out, int out_size, void* d_ws, size_t ws_size,
                              hipStream_t stream){
  const float* hs = (const float*)d_in[0];
  const float* Wq = (const float*)d_in[1];
  const float* bq = (const float*)d_in[2];
  const float* Wk = (const float*)d_in[3];
  const float* bk = (const float*)d_in[4];
  const float* Wv = (const float*)d_in[5];
  const float* bv = (const float*)d_in[6];
  const int*   g  = (const int*)d_in[7];
  const float* am = (const float*)d_in[8];
  float* out = (float*)d_out;

  char* w = (char*)d_ws;
  auto alloc=[&](size_t bytes)->char*{ char* p=w; w += (bytes+255)&~(size_t)255; return p; };
  short* Xb  = (short*)alloc((size_t)1024*768*2);
  short* WT  = (short*)alloc((size_t)3*768*768*2);
  short* qs  = (short*)alloc((size_t)1024*768*2);
  short* ks  = (short*)alloc((size_t)1024*768*2);
  short* vs  = (short*)alloc((size_t)1024*768*2);
  short* vT  = (short*)alloc((size_t)12*64*1024*2);
  short* WG  = (short*)alloc((size_t)12*1024*1024*2);
  short* Am  = (short*)alloc((size_t)12*1024*1024*2);
  short* AmT = (short*)alloc((size_t)12*1024*1024*2);  // later reused as V
  short* Tm  = (short*)alloc((size_t)12*1024*1024*2);  // later reused as L
  short* A2  = (short*)alloc((size_t)12*1024*1024*2);
  short* A3T = (short*)alloc((size_t)12*1024*1024*2);
  float* od  = (float*)alloc((size_t)12*1024*4);
  float* rh  = (float*)alloc((size_t)64*4);
  float* bmf = (float*)alloc((size_t)1024*4);
  float* dv  = (float*)alloc((size_t)12*1024*4);
  float* rab = (float*)alloc((size_t)12*1024*4);

  hipMemsetAsync(od,  0, (size_t)12*1024*4, stream);
  hipMemsetAsync(rab, 0, (size_t)12*1024*4, stream);

  cvt_x<<<384,256,0,stream>>>(hs, Xb);
  cvt_wt<<<144,256,0,stream>>>(Wq, WT);
  cvt_wt<<<144,256,0,stream>>>(Wk, WT + (size_t)768*768);
  cvt_wt<<<144,256,0,stream>>>(Wv, WT + (size_t)2*768*768);
  bmask_k<<<4,256,0,stream>>>(am, bmf);
  qkv_gemm<<<dim3(48,3),256,0,stream>>>(Xb, WT, bq,bk,bv, qs,ks,vs);
  vtrans<<<dim3(16,12),256,0,stream>>>(vs, vT);
  wg_gemm<<<dim3(64,12),256,0,stream>>>(ks, qs, g, bmf, WG, od);
  rhos_k<<<12,256,0,stream>>>(od, rh);
  amat_t<<<dim3(256,12),256,0,stream>>>(WG, od, rh, Am, AmT, Tm);

  const float b1=-0.5f, b2=-0.125f, b3=-1.f/16.f, b4=-5.f/128.f, b5=-7.f/256.f;
  short* V = AmT;   // AmT dead after G2
  short* L = Tm;    // Tm dead after G3
  // G1: A2 = Am * AmT^T (= A^2)
  gemm8p_plain<<<192,512,0,stream>>>(Am, AmT, A2);
  // G2: A3T = AmT * A2^T (= (A^3)^T)
  gemm8p_plain<<<192,512,0,stream>>>(AmT, A2, A3T);
  // G3: V = T * A3 + b3 I + b4 A + b5 A2
  gemm8p_epi<<<192,512,0,stream>>>(Tm, A3T, V, Am, A2, b3,b4,b5);
  // G4: L = V * A3 + I + b1 A + b2 A2   (+ fused row |L| sums and diagonal)
  gemm8p_epi_stat<<<192,512,0,stream>>>(V, A3T, L, Am, A2, 1.0f,b1,b2, rab, dv);

  attn_k<<<dim3(8,12),256,0,stream>>>(WG, L, vT, vs, od, dv, rab, out);
}

// Round 5
// 281.361 us; speedup vs baseline: 1.4173x; 1.0409x over previous
//
#include <hip/hip_runtime.h>
#include <hip/hip_bf16.h>

typedef __attribute__((ext_vector_type(4))) float f32x4;
typedef __attribute__((ext_vector_type(8))) short s16x8;

typedef const __attribute__((address_space(1))) void* gptr_t;
typedef __attribute__((address_space(3))) void* lptr_t;

__device__ __forceinline__ short f2b(float f){ __hip_bfloat16 h=__float2bfloat16(f); return *(short*)&h; }
__device__ __forceinline__ float b2f(short s){ __hip_bfloat16 h; *(short*)&h = s; return __bfloat162float(h); }

__device__ __forceinline__ void gl_lds16(const void* g, void* l){
  __builtin_amdgcn_global_load_lds((gptr_t)g, (lptr_t)l, 16, 0, 0);
}

// ---------------- small prep kernels ----------------

__global__ __launch_bounds__(256) void cvt_x(const float* __restrict__ X, short* __restrict__ Xb){
  int i = blockIdx.x*256 + threadIdx.x;
  const float4* p = (const float4*)(X + (size_t)i*8);
  float4 a = p[0], b = p[1];
  s16x8 o;
  o[0]=f2b(a.x); o[1]=f2b(a.y); o[2]=f2b(a.z); o[3]=f2b(a.w);
  o[4]=f2b(b.x); o[5]=f2b(b.y); o[6]=f2b(b.z); o[7]=f2b(b.w);
  *(s16x8*)(Xb + (size_t)i*8) = o;
}

__global__ __launch_bounds__(256) void cvt_wt(const float* __restrict__ W, short* __restrict__ WT){
  __shared__ short tile[64][72];
  int bl = blockIdx.x % 12, bn = blockIdx.x / 12;
  int l0 = bl*64, n0 = bn*64;
  int t = threadIdx.x;
  #pragma unroll
  for (int p=0;p<4;p++){
    int lr = p*16 + (t>>4);
    int nc = (t&15)*4;
    float4 v = *(const float4*)(W + (size_t)(l0+lr)*768 + n0 + nc);
    tile[lr][nc+0]=f2b(v.x); tile[lr][nc+1]=f2b(v.y); tile[lr][nc+2]=f2b(v.z); tile[lr][nc+3]=f2b(v.w);
  }
  __syncthreads();
  #pragma unroll
  for (int p=0;p<2;p++){
    int nr = p*32 + (t>>3);
    int lc = (t&7)*8;
    s16x8 o;
    #pragma unroll
    for(int u=0;u<8;u++) o[u] = tile[lc+u][nr];
    *(s16x8*)(WT + (size_t)(n0+nr)*768 + l0 + lc) = o;
  }
}

__global__ __launch_bounds__(256) void vtrans(const short* __restrict__ vs, short* __restrict__ vT){
  __shared__ short tile[64][72];
  int h = blockIdx.y; int i0 = blockIdx.x*64;
  int t = threadIdx.x;
  #pragma unroll
  for(int p=0;p<2;p++){
    int ir = p*32 + (t>>3); int c8=(t&7)*8;
    *(s16x8*)&tile[ir][c8] = *(const s16x8*)(vs + (size_t)(i0+ir)*768 + h*64 + c8);
  }
  __syncthreads();
  #pragma unroll
  for(int p=0;p<2;p++){
    int dr = p*32 + (t>>3); int i8=(t&7)*8;
    s16x8 o;
    #pragma unroll
    for(int u=0;u<8;u++) o[u]=tile[i8+u][dr];
    *(s16x8*)(vT + ((size_t)h*64 + dr)*1024 + i0 + i8) = o;
  }
}

// ---------------- QKV projection GEMM ----------------
__global__ __launch_bounds__(256) void qkv_gemm(const short* __restrict__ Xb, const short* __restrict__ WT,
      const float* __restrict__ bq, const float* __restrict__ bk, const float* __restrict__ bv,
      short* __restrict__ qs, short* __restrict__ ks, short* __restrict__ vs){
  __shared__ short lA[128*32], lB[128*32];
  int mat = blockIdx.y;
  const short* B = WT + (size_t)mat*768*768;
  const float* bias = mat==0?bq:(mat==1?bk:bv);
  short* outp = mat==0?qs:(mat==1?ks:vs);
  float scale = mat==0 ? 0.125f : 1.0f;
  int tm = (blockIdx.x / 6)*128, tn = (blockIdx.x % 6)*128;
  int t=threadIdx.x, wave=t>>6, lane=t&63;
  int srow=t>>2, scol=(t&3)*8;
  int wm=(wave>>1)*64, wn=(wave&1)*64;
  f32x4 acc[4][4]={};
  for (int k0=0;k0<768;k0+=32){
    #pragma unroll
    for(int r=0;r<2;++r){
      gl_lds16(Xb + (size_t)(tm+srow+r*64)*768 + k0 + scol, lA + r*2048 + wave*512);
      gl_lds16(B  + (size_t)(tn+srow+r*64)*768 + k0 + scol, lB + r*2048 + wave*512);
    }
    __syncthreads();
    int krow=(lane>>4)*8, rl=lane&15;
    s16x8 af[4], bfr[4];
    #pragma unroll
    for(int m=0;m<4;m++) af[m] = *(s16x8*)&lA[(wm+m*16+rl)*32 + krow];
    #pragma unroll
    for(int n=0;n<4;n++) bfr[n] = *(s16x8*)&lB[(wn+n*16+rl)*32 + krow];
    #pragma unroll
    for(int m=0;m<4;m++)
      #pragma unroll
      for(int n=0;n<4;n++)
        acc[m][n]=__builtin_amdgcn_mfma_f32_16x16x32_bf16(af[m],bfr[n],acc[m][n],0,0,0);
    __syncthreads();
  }
  int r0 = tm + wm + (lane>>4)*4, c0 = tn + wn + (lane&15);
  #pragma unroll
  for(int m=0;m<4;m++)
    #pragma unroll
    for(int n=0;n<4;n++){
      int col = c0 + n*16; float bb = bias[col];
      #pragma unroll
      for(int r=0;r<4;r++){
        int row = r0 + m*16 + r;
        outp[(size_t)row*768 + col] = f2b((acc[m][n][r] + bb)*scale);
      }
    }
}

// ---------------- W_G = exp(K Q^T) masked, + row sums (token mask inlined) ----------------
__global__ __launch_bounds__(256) void wg_gemm(const short* __restrict__ kb, const short* __restrict__ qb,
      const int* __restrict__ g, const float* __restrict__ am,
      short* __restrict__ WG, float* __restrict__ od){
  __shared__ short lK[128*64], lQ[128*64];
  int h=blockIdx.y;
  int tm=(blockIdx.x>>3)*128, tn=(blockIdx.x&7)*128;
  int t=threadIdx.x, wave=t>>6, lane=t&63;
  int srow=t>>3, scol=(t&7)*8;
  int wm=(wave>>1)*64, wn=(wave&1)*64;
  #pragma unroll
  for(int r=0;r<4;++r){
    gl_lds16(kb + (size_t)(tm+srow+r*32)*768 + h*64 + scol, lK + r*2048 + wave*512);
    gl_lds16(qb + (size_t)(tn+srow+r*32)*768 + h*64 + scol, lQ + r*2048 + wave*512);
  }
  __syncthreads();
  int rl=lane&15;
  f32x4 acc[4][4]={};
  #pragma unroll
  for(int ks=0;ks<2;ks++){
    int krow=ks*32+(lane>>4)*8;
    s16x8 af[4], bfr[4];
    #pragma unroll
    for(int m=0;m<4;m++) af[m]=*(s16x8*)&lK[(wm+m*16+rl)*64+krow];
    #pragma unroll
    for(int n=0;n<4;n++) bfr[n]=*(s16x8*)&lQ[(wn+n*16+rl)*64+krow];
    #pragma unroll
    for(int m=0;m<4;m++)
      #pragma unroll
      for(int n=0;n<4;n++)
        acc[m][n]=__builtin_amdgcn_mfma_f32_16x16x32_bf16(af[m],bfr[n],acc[m][n],0,0,0);
  }
  size_t hm=(size_t)h<<20;
  int r0=tm+wm+(lane>>4)*4, c0=tn+wn+rl;
  #pragma unroll
  for(int m=0;m<4;m++){
    float rs[4]={0.f,0.f,0.f,0.f};
    #pragma unroll
    for(int n=0;n<4;n++){
      int col=c0+n*16;
      bool mc = am[col] >= 0.0f;
      #pragma unroll
      for(int r=0;r<4;r++){
        int row=r0+m*16+r;
        float e = expf(acc[m][n][r]);
        float w = (g[(size_t)row*1024+col]>0 && am[row]>=0.0f && mc) ? e : 0.f;
        WG[hm+(size_t)row*1024+col]=f2b(w);
        rs[r]+=w;
      }
    }
    #pragma unroll
    for(int r=0;r<4;r++){
      float s=rs[r];
      #pragma unroll
      for(int off=1;off<16;off<<=1) s+=__shfl_xor(s,off);
      if(rl==0) atomicAdd(&od[(h<<10)+r0+m*16+r], s);
    }
  }
}

__global__ void rhos_k(const float* __restrict__ od, float* __restrict__ rhos){
  __shared__ float red[256];
  int h = blockIdx.x, t = threadIdx.x;
  float m = -1e30f;
  for (int i=t;i<1024;i+=256) m = fmaxf(m, od[(h<<10)+i]);
  red[t]=m; __syncthreads();
  for(int s=128;s>0;s>>=1){ if(t<s) red[t]=fmaxf(red[t],red[t+s]); __syncthreads(); }
  if(t==0) rhos[h]=red[0];
}

// Am = (WG + diag(rho-od))/rho ; AmT = Am^T ; T = b7*Am + b6*I
__global__ __launch_bounds__(256) void amat_t(const short* __restrict__ WG, const float* __restrict__ od,
      const float* __restrict__ rhos, short* __restrict__ Am, short* __restrict__ AmT,
      short* __restrict__ T){
  __shared__ short tile[64][72];
  const float b7 = -33.f/2048.f, b6 = -21.f/1024.f;
  int h = blockIdx.y; int bx = blockIdx.x;
  int rb = bx >> 4, cb = bx & 15;
  int r0 = rb*64, c0 = cb*64;
  float rho = rhos[h]; float inv = 1.0f/fmaxf(rho,1e-30f);
  size_t hm = (size_t)h<<20;
  int t = threadIdx.x;
  #pragma unroll
  for(int p=0;p<2;p++){
    int r = p*32 + (t>>3); int c8 = (t&7)*8;
    size_t base = hm + (size_t)(r0+r)*1024 + c0 + c8;
    s16x8 w = *(const s16x8*)(WG + base);
    s16x8 oa, ot;
    float dadd = (rho - od[(h<<10)+r0+r])*inv;
    #pragma unroll
    for(int u=0;u<8;u++){
      bool dg = (rb==cb) && ((c8+u)==r);
      float a = b2f(w[u])*inv + (dg ? dadd : 0.f);
      oa[u]=f2b(a);
      ot[u]=f2b(b7*a + (dg ? b6 : 0.f));
      tile[r][c8+u]=oa[u];
    }
    *(s16x8*)(Am+base)=oa; *(s16x8*)(T+base)=ot;
  }
  __syncthreads();
  #pragma unroll
  for(int p=0;p<2;p++){
    int c = p*32 + (t>>3); int r8 = (t&7)*8;
    s16x8 o;
    #pragma unroll
    for(int u=0;u<8;u++) o[u]=tile[r8+u][c];
    *(s16x8*)(AmT + hm + (size_t)(c0+c)*1024 + r0 + r8) = o;
  }
}

// ======== big GEMMs: 128^2 tile, double-buffered BK=32 (T3-min 2-phase), T1 swizzle ========
// D = X*Y^T per head. grid = 768 = 12 heads x 64 tiles; 768%8==0 -> simple XCD swizzle bijective.
// LDS 32 KiB -> 5 blocks/CU cap; one __syncthreads per K-step (built-in vmcnt(0)+lgkmcnt(0) drain,
// covered by the preceding ds_read+MFMA of the CURRENT buffer).
#define GEMM2P_PROLOG \
  __shared__ short lA[2][4096], lB[2][4096]; \
  int wg = ((int)blockIdx.x & 7)*96 + ((int)blockIdx.x >> 3); \
  int h = wg >> 6; int tile = wg & 63; \
  int tm=(tile>>3)*128, tn=(tile&7)*128; \
  size_t hm=(size_t)h<<20; \
  const short* Ag = A + hm; const short* Bg = B + hm; \
  int t=threadIdx.x, wave=t>>6, lane=t&63; \
  int srow=t>>2, scol=(t&3)*8; \
  int wm=(wave>>1)*64, wn=(wave&1)*64; \
  int krow=(lane>>4)*8, rl=lane&15; \
  f32x4 acc[4][4]={}; \
  _Pragma("unroll") \
  for(int r=0;r<2;++r){ \
    gl_lds16(Ag + (size_t)(tm+srow+r*64)*1024 + scol, &lA[0][r*2048 + wave*512]); \
    gl_lds16(Bg + (size_t)(tn+srow+r*64)*1024 + scol, &lB[0][r*2048 + wave*512]); \
  } \
  __syncthreads(); \
  int cur=0; \
  _Pragma("unroll 1") \
  for(int k0=32;k0<1024;k0+=32){ \
    _Pragma("unroll") \
    for(int r=0;r<2;++r){ \
      gl_lds16(Ag + (size_t)(tm+srow+r*64)*1024 + k0 + scol, &lA[cur^1][r*2048 + wave*512]); \
      gl_lds16(Bg + (size_t)(tn+srow+r*64)*1024 + k0 + scol, &lB[cur^1][r*2048 + wave*512]); \
    } \
    s16x8 af[4], bfr[4]; \
    _Pragma("unroll") \
    for(int m=0;m<4;m++) af[m]=*(s16x8*)&lA[cur][(wm+m*16+rl)*32+krow]; \
    _Pragma("unroll") \
    for(int n=0;n<4;n++) bfr[n]=*(s16x8*)&lB[cur][(wn+n*16+rl)*32+krow]; \
    __builtin_amdgcn_s_setprio(1); \
    _Pragma("unroll") \
    for(int m=0;m<4;m++) \
      _Pragma("unroll") \
      for(int n=0;n<4;n++) \
        acc[m][n]=__builtin_amdgcn_mfma_f32_16x16x32_bf16(af[m],bfr[n],acc[m][n],0,0,0); \
    __builtin_amdgcn_s_setprio(0); \
    __syncthreads(); \
    cur^=1; \
  } \
  { s16x8 af[4], bfr[4]; \
    _Pragma("unroll") \
    for(int m=0;m<4;m++) af[m]=*(s16x8*)&lA[cur][(wm+m*16+rl)*32+krow]; \
    _Pragma("unroll") \
    for(int n=0;n<4;n++) bfr[n]=*(s16x8*)&lB[cur][(wn+n*16+rl)*32+krow]; \
    __builtin_amdgcn_s_setprio(1); \
    _Pragma("unroll") \
    for(int m=0;m<4;m++) \
      _Pragma("unroll") \
      for(int n=0;n<4;n++) \
        acc[m][n]=__builtin_amdgcn_mfma_f32_16x16x32_bf16(af[m],bfr[n],acc[m][n],0,0,0); \
    __builtin_amdgcn_s_setprio(0); \
  } \
  int r0=tm+wm+(lane>>4)*4, c0=tn+wn+(lane&15);

__global__ __launch_bounds__(256) void gemm2p_plain(const short* __restrict__ A, const short* __restrict__ B,
      short* __restrict__ D){
  GEMM2P_PROLOG
  short* Dg = D + hm;
  #pragma unroll
  for(int m=0;m<4;m++)
    #pragma unroll
    for(int n=0;n<4;n++){
      int col=c0+n*16;
      #pragma unroll
      for(int r=0;r<4;r++)
        Dg[(size_t)(r0+m*16+r)*1024 + col]=f2b(acc[m][n][r]);
    }
}

__global__ __launch_bounds__(256) void gemm2p_epi(const short* __restrict__ A, const short* __restrict__ B,
      short* __restrict__ D, const short* __restrict__ E1, const short* __restrict__ E2,
      float c0c, float cA, float cB){
  GEMM2P_PROLOG
  short* Dg = D + hm;
  const short* E1g = E1 + hm; const short* E2g = E2 + hm;
  #pragma unroll
  for(int m=0;m<4;m++)
    #pragma unroll
    for(int n=0;n<4;n++){
      int col=c0+n*16;
      #pragma unroll
      for(int r=0;r<4;r++){
        int row=r0+m*16+r;
        size_t e = (size_t)row*1024 + col;
        float v = acc[m][n][r] + cA*b2f(E1g[e]) + cB*b2f(E2g[e]);
        if(row==col) v += c0c;
        Dg[e]=f2b(v);
      }
    }
}

__global__ __launch_bounds__(256) void gemm2p_epi_stat(const short* __restrict__ A, const short* __restrict__ B,
      short* __restrict__ D, const short* __restrict__ E1, const short* __restrict__ E2,
      float c0c, float cA, float cB, float* __restrict__ rowabs, float* __restrict__ dvp){
  GEMM2P_PROLOG
  short* Dg = D + hm;
  const short* E1g = E1 + hm; const short* E2g = E2 + hm;
  #pragma unroll
  for(int m=0;m<4;m++){
    float rs[4]={0.f,0.f,0.f,0.f};
    #pragma unroll
    for(int n=0;n<4;n++){
      int col=c0+n*16;
      #pragma unroll
      for(int r=0;r<4;r++){
        int row=r0+m*16+r;
        size_t e = (size_t)row*1024 + col;
        float v = acc[m][n][r] + cA*b2f(E1g[e]) + cB*b2f(E2g[e]);
        if(row==col){ v += c0c; dvp[(h<<10)+row] = v; }
        rs[r] += fabsf(v);
        Dg[e]=f2b(v);
      }
    }
    #pragma unroll
    for(int r=0;r<4;r++){
      float s=rs[r];
      #pragma unroll
      for(int off=1;off<16;off<<=1) s+=__shfl_xor(s,off);
      if(rl==0) atomicAdd(&rowabs[(h<<10)+r0+m*16+r], s);
    }
  }
}

// ---------------- final: attn = .8*(WG/od)@v + .2*(d_i v_i - L@v)/r_i ----------------
__global__ __launch_bounds__(256) void attn_k(const short* __restrict__ WG, const short* __restrict__ L,
    const short* __restrict__ vT, const short* __restrict__ vs,
    const float* __restrict__ od, const float* __restrict__ dv, const float* __restrict__ rowabs,
    float* __restrict__ out){
  __shared__ short lW[128*32], lL[128*32], lV[64*32];
  int h=blockIdx.y, tm=blockIdx.x*128;
  size_t hm=(size_t)h<<20;
  int t=threadIdx.x, wave=t>>6, lane=t&63;
  int srow=t>>2, scol=(t&3)*8;
  f32x4 a1[2][4]={}, a2[2][4]={};
  for(int j0=0;j0<1024;j0+=32){
    #pragma unroll
    for(int r=0;r<2;++r){
      gl_lds16(WG + hm + (size_t)(tm+srow+r*64)*1024 + j0 + scol, lW + r*2048 + wave*512);
      gl_lds16(L  + hm + (size_t)(tm+srow+r*64)*1024 + j0 + scol, lL + r*2048 + wave*512);
    }
    gl_lds16(vT + ((size_t)h*64 + srow)*1024 + j0 + scol, lV + wave*512);
    __syncthreads();
    int krow=(lane>>4)*8, rl=lane&15;
    s16x8 fw[2], fl[2], fv[4];
    #pragma unroll
    for(int m=0;m<2;m++){
      fw[m]=*(s16x8*)&lW[(wave*32+m*16+rl)*32+krow];
      fl[m]=*(s16x8*)&lL[(wave*32+m*16+rl)*32+krow];
    }
    #pragma unroll
    for(int n=0;n<4;n++) fv[n]=*(s16x8*)&lV[(n*16+rl)*32+krow];
    #pragma unroll
    for(int m=0;m<2;m++)
      #pragma unroll
      for(int n=0;n<4;n++){
        a1[m][n]=__builtin_amdgcn_mfma_f32_16x16x32_bf16(fw[m],fv[n],a1[m][n],0,0,0);
        a2[m][n]=__builtin_amdgcn_mfma_f32_16x16x32_bf16(fl[m],fv[n],a2[m][n],0,0,0);
      }
    __syncthreads();
  }
  #pragma unroll
  for(int m=0;m<2;m++)
    #pragma unroll
    for(int r=0;r<4;r++){
      int row = tm + wave*32 + m*16 + (lane>>4)*4 + r;
      float invod = 1.0f/fmaxf(od[(h<<10)+row], 1e-12f);
      float dvi = dv[(h<<10)+row];
      float ivr = 1.0f/fmaxf(rowabs[(h<<10)+row] - fabsf(dvi), 1e-12f);
      #pragma unroll
      for(int n=0;n<4;n++){
        int d = n*16 + (lane&15);
        float vv = b2f(vs[(size_t)row*768 + h*64 + d]);
        out[(((size_t)h<<10)+row)*64 + d] = 0.8f*a1[m][n][r]*invod + 0.2f*(dvi*vv - a2[m][n][r])*ivr;
      }
    }
}

// ---------------- launch ----------------
extern "C" void kernel_launch(void* const* d_in, const int* in_sizes, int n_in,
                              void* d_out, int out_size, void* d_ws, size_t ws_size,
                              hipStream_t stream){
  const float* hs = (const float*)d_in[0];
  const float* Wq = (const float*)d_in[1];
  const float* bq = (const float*)d_in[2];
  const float* Wk = (const float*)d_in[3];
  const float* bk = (const float*)d_in[4];
  const float* Wv = (const float*)d_in[5];
  const float* bv = (const float*)d_in[6];
  const int*   g  = (const int*)d_in[7];
  const float* am = (const float*)d_in[8];
  float* out = (float*)d_out;

  char* w = (char*)d_ws;
  auto alloc=[&](size_t bytes)->char*{ char* p=w; w += (bytes+255)&~(size_t)255; return p; };
  short* Xb  = (short*)alloc((size_t)1024*768*2);
  short* WT  = (short*)alloc((size_t)3*768*768*2);
  short* qs  = (short*)alloc((size_t)1024*768*2);
  short* ks  = (short*)alloc((size_t)1024*768*2);
  short* vs  = (short*)alloc((size_t)1024*768*2);
  short* vT  = (short*)alloc((size_t)12*64*1024*2);
  short* WG  = (short*)alloc((size_t)12*1024*1024*2);
  short* Am  = (short*)alloc((size_t)12*1024*1024*2);
  short* AmT = (short*)alloc((size_t)12*1024*1024*2);  // later reused as V
  short* Tm  = (short*)alloc((size_t)12*1024*1024*2);  // later reused as L
  short* A2  = (short*)alloc((size_t)12*1024*1024*2);
  short* A3T = (short*)alloc((size_t)12*1024*1024*2);
  float* od  = (float*)alloc((size_t)12*1024*4);
  float* rh  = (float*)alloc((size_t)64*4);
  float* dv  = (float*)alloc((size_t)12*1024*4);
  float* rab = (float*)alloc((size_t)12*1024*4);

  hipMemsetAsync(od,  0, (size_t)12*1024*4, stream);
  hipMemsetAsync(rab, 0, (size_t)12*1024*4, stream);

  cvt_x<<<384,256,0,stream>>>(hs, Xb);
  cvt_wt<<<144,256,0,stream>>>(Wq, WT);
  cvt_wt<<<144,256,0,stream>>>(Wk, WT + (size_t)768*768);
  cvt_wt<<<144,256,0,stream>>>(Wv, WT + (size_t)2*768*768);
  qkv_gemm<<<dim3(48,3),256,0,stream>>>(Xb, WT, bq,bk,bv, qs,ks,vs);
  vtrans<<<dim3(16,12),256,0,stream>>>(vs, vT);
  wg_gemm<<<dim3(64,12),256,0,stream>>>(ks, qs, g, am, WG, od);
  rhos_k<<<12,256,0,stream>>>(od, rh);
  amat_t<<<dim3(256,12),256,0,stream>>>(WG, od, rh, Am, AmT, Tm);

  const float b1=-0.5f, b2=-0.125f, b3=-1.f/16.f, b4=-5.f/128.f, b5=-7.f/256.f;
  short* V = AmT;   // AmT dead after G2
  short* L = Tm;    // Tm dead after G3
  // G1: A2 = Am * AmT^T (= A^2)
  gemm2p_plain<<<768,256,0,stream>>>(Am, AmT, A2);
  // G2: A3T = AmT * A2^T (= (A^3)^T)
  gemm2p_plain<<<768,256,0,stream>>>(AmT, A2, A3T);
  // G3: V = T * A3 + b3 I + b4 A + b5 A2
  gemm2p_epi<<<768,256,0,stream>>>(Tm, A3T, V, Am, A2, b3,b4,b5);
  // G4: L = V * A3 + I + b1 A + b2 A2   (+ fused row |L| sums and diagonal)
  gemm2p_epi_stat<<<768,256,0,stream>>>(V, A3T, L, Am, A2, 1.0f,b1,b2, rab, dv);

  attn_k<<<dim3(8,12),256,0,stream>>>(WG, L, vT, vs, od, dv, rab, out);
}